// Round 11
// baseline (1276.304 us; speedup 1.0000x reference)
//
#include <hip/hip_runtime.h>
#include <hip/hip_bf16.h>

// GraphConvNet on MI355X — round 11: weights-stationary PERSISTENT edge kernel.
// Evidence: r4/r9/r10 all pin edge at ~287us with wildly different VALU load
// and occupancy (44->52% changed nothing). Per-SIMD pipes all <10% busy.
// -> wall = per-wave 168KB weight stream from L2 (~200cyc) consumed in 21
//    vmcnt-serialized bursts. Fix: stage Ws0 (96KB, 57% of stream, the
//    12-chunk step-GEMM1 chain) in LDS once per persistent block.
//   * edge grid: 256 blocks x 512 thr (8 waves, 1 block/CU), grid-stride
//     over 128-edge tiles; barrier only after the one-time stage.
//   * LDS 130.8KB static (96 Ws0 + 34.8 Hw) — gfx950 allows 160KB/CU.
//   * everything else identical to r10 (zero-atomic, segsum, sorted feats).
//
// MFMA fragment facts (guide §3, m89/m91/m120 verified):
//   A: lane holds A[m=lane&15][k=(lane>>4)*8+j]
//   B: lane holds B[k=(lane>>4)*8+j][n=lane&15]
//   C/D: lane reg r holds C[row=(lane>>4)*4+r][col=lane&15]

typedef __bf16 bf16;
typedef __attribute__((ext_vector_type(8))) __bf16 bf16x8;
typedef __attribute__((ext_vector_type(2))) __bf16 bf16x2;
typedef __attribute__((ext_vector_type(4))) float f32x4;

__device__ __forceinline__ float gelu_t(float x) {
    // exact identity: 0.5x(1+tanh(u)) == x*sigmoid(2u) = x/(1+exp(-2u))
    const float kn0 = -1.5957691216057308f;   // -2*sqrt(2/pi)
    const float kn1 = -0.07135481627159855f;  // -2*sqrt(2/pi)*0.044715
    float x2 = x * x;
    float w = x * __builtin_fmaf(kn1, x2, kn0);
    float e = __expf(w);
    return __fdividef(x, 1.0f + e);
}

// ---------------- weight packing: [K,128] fp32 -> bf16 [K/8][128][8] ----------------
struct PackDesc { const float* src; int Kcopy; int dstOff; };
struct PackArgs { PackDesc d[13]; };

__global__ __launch_bounds__(256) void pack_all_kernel(PackArgs pa, bf16* dst, int total) {
    int i = blockIdx.x * 256 + threadIdx.x;
    if (i >= total) return;
    int s = 0;
#pragma unroll
    for (int j = 1; j < 13; ++j) if (i >= pa.d[j].dstOff) s = j;
    int local = i - pa.d[s].dstOff;
    int k = local >> 7, n = local & 127;
    float v = (k < pa.d[s].Kcopy) ? pa.d[s].src[(size_t)k * 128 + n] : 0.0f;
    dst[pa.d[s].dstOff + ((k >> 3) * 128 + n) * 8 + (k & 7)] = (bf16)v;
}

__global__ void fold_bias_kernel(const float* g, const float* euW0, const float* eub0,
                                 const float* nuW0, const float* nub0,
                                 float* eu_eff, float* nu_eff) {
    int t = threadIdx.x;
    if (t < 128) {
        float g0 = g[0], g1 = g[1];
#pragma unroll
        for (int s = 0; s < 2; ++s) {
            eu_eff[s * 128 + t] = eub0[s * 128 + t]
                + g0 * euW0[((size_t)s * 386 + 384) * 128 + t]
                + g1 * euW0[((size_t)s * 386 + 385) * 128 + t];
            nu_eff[s * 128 + t] = nub0[s * 128 + t]
                + g0 * nuW0[((size_t)s * 258 + 256) * 128 + t]
                + g1 * nuW0[((size_t)s * 258 + 257) * 128 + t];
        }
    }
}

__global__ __launch_bounds__(256) void zero_kernel(float4* p, int n4) {
    int i = blockIdx.x * 256 + threadIdx.x;
    if (i < n4) p[i] = float4{0.0f, 0.0f, 0.0f, 0.0f};
}

// ---------------- receiver-sort (counting sort) ----------------
__global__ __launch_bounds__(256) void hist_kernel(const int* __restrict__ recv,
                                                   int* __restrict__ deg, int E) {
    int e = blockIdx.x * 256 + threadIdx.x;
    if (e < E) atomicAdd(&deg[recv[e]], 1);
}

__global__ __launch_bounds__(256) void scan_part_kernel(const int* __restrict__ deg,
                                                        int* __restrict__ cursor,
                                                        int* __restrict__ bsum, int n) {
    __shared__ int tmp[256];
    int t = threadIdx.x, g = blockIdx.x * 256 + t;
    int v = (g < n) ? deg[g] : 0;
    tmp[t] = v; __syncthreads();
#pragma unroll
    for (int o = 1; o < 256; o <<= 1) {
        int x = (t >= o) ? tmp[t - o] : 0;
        __syncthreads();
        tmp[t] += x;
        __syncthreads();
    }
    if (g < n) cursor[g] = tmp[t] - v;
    if (t == 255) bsum[blockIdx.x] = tmp[255];
}

__global__ void scan_top_kernel(int* bsum, int nb) {  // single block, nb<=256
    __shared__ int tmp[256];
    int t = threadIdx.x;
    int v = (t < nb) ? bsum[t] : 0;
    tmp[t] = v; __syncthreads();
#pragma unroll
    for (int o = 1; o < 256; o <<= 1) {
        int x = (t >= o) ? tmp[t - o] : 0;
        __syncthreads();
        tmp[t] += x;
        __syncthreads();
    }
    if (t < nb) bsum[t] = tmp[t] - v;
}

__global__ __launch_bounds__(256) void scan_add_kernel(int* __restrict__ cursor,
                                                       const int* __restrict__ bsum, int n) {
    int g = blockIdx.x * 256 + threadIdx.x;
    if (g < n) cursor[g] += bsum[blockIdx.x];
}

// scatter: also pre-sorts raw edge features (edges_s[pos] = edges[e])
__global__ __launch_bounds__(256) void scatter_kernel(
    const int* __restrict__ send, const int* __restrict__ recv,
    const float* __restrict__ edges_raw, int* __restrict__ cursor,
    float* __restrict__ edges_s, int* __restrict__ sendp, int* __restrict__ recvp, int E) {
    int e = blockIdx.x * 256 + threadIdx.x;
    if (e >= E) return;
    int r = recv[e];
    int pos = atomicAdd(&cursor[r], 1);
    sendp[pos] = send[e]; recvp[pos] = r;
    edges_s[(size_t)pos * 3]     = edges_raw[(size_t)e * 3];
    edges_s[(size_t)pos * 3 + 1] = edges_raw[(size_t)e * 3 + 1];
    edges_s[(size_t)pos * 3 + 2] = edges_raw[(size_t)e * 3 + 2];
}
// after scatter: cursor[i] == end offset of node i's segment (CSR row end)

// ---------------- segment-sum: recvb[i] = sum of newe rows in [start,end) ----------------
__global__ __launch_bounds__(256) void segsum_kernel(const bf16* __restrict__ newe,
                                                     const int* __restrict__ endoff,
                                                     bf16* __restrict__ recvb, int N) {
    int node = blockIdx.x * 4 + (threadIdx.x >> 6);
    if (node >= N) return;
    int lane = threadIdx.x & 63;
    int start = (node == 0) ? 0 : endoff[node - 1];
    int end = endoff[node];
    float s0 = 0.0f, s1 = 0.0f, t0 = 0.0f, t1 = 0.0f;
    int e = start;
    for (; e + 1 < end; e += 2) {
        bf16x2 v = *(const bf16x2*)(newe + (size_t)e * 128 + lane * 2);
        bf16x2 u = *(const bf16x2*)(newe + (size_t)(e + 1) * 128 + lane * 2);
        s0 += (float)v[0]; s1 += (float)v[1];
        t0 += (float)u[0]; t1 += (float)u[1];
    }
    if (e < end) {
        bf16x2 v = *(const bf16x2*)(newe + (size_t)e * 128 + lane * 2);
        s0 += (float)v[0]; s1 += (float)v[1];
    }
    bf16x2 o; o[0] = (bf16)(s0 + t0); o[1] = (bf16)(s1 + t1);
    *(bf16x2*)(recvb + (size_t)node * 128 + lane * 2) = o;
}

// ---------------- PERSISTENT edge megakernel ----------------
// 256 blocks x 512 threads (8 waves). Stage Ws0 (96KB) into LDS once, then
// grid-stride over 128-edge tiles. Barrier only after stage; tile loop is
// barrier-free (Ws0L read-only, Hw wave-private, waves own their 16 rows).
// STEP 0: new_e1 = MLP_s0(concat(eh0, nh_s, nh_r)+g)        ; newe <- new_e1
// STEP 1: eh1 = LN(eh0+newe1); new_e2 = MLP_s1(concat(...)) ; newe <- new_e2
template <int STEP>
__global__ __launch_bounds__(512, 2) void edge_kernel(
    const float* __restrict__ edges_s,
    const int* __restrict__ sendp, const int* __restrict__ recvp,
    const bf16* __restrict__ nh_b, bf16* __restrict__ newe,
    const bf16* __restrict__ We0, const float* __restrict__ be0,
    const bf16* __restrict__ We1, const float* __restrict__ be1,
    const float* __restrict__ ln_s, const float* __restrict__ ln_b,
    const bf16* __restrict__ Ws0, const float* __restrict__ bs0,
    const bf16* __restrict__ Ws1, const float* __restrict__ bs1,
    int E)
{
    __shared__ __align__(16) bf16 Ws0L[48 * 128 * 8];   // 96 KB: staged Ws0 (packed layout)
    __shared__ __align__(16) bf16 Hsep[8 * 16 * 136];   // 34.8 KB: 8 wave-private slabs

    // one-time cooperative stage of Ws0 into LDS
    {
        const uint4* src = (const uint4*)Ws0;
        uint4* dst = (uint4*)Ws0L;
        for (int i = threadIdx.x; i < (48 * 128 * 8) / 8; i += 512)
            dst[i] = src[i];
    }
    __syncthreads();

    const int tid = threadIdx.x, lane = tid & 63, w = tid >> 6;
    const int n16 = lane & 15, quad = lane >> 4;
    bf16* Hw = &Hsep[w * 16 * 136];
    const f32x4 z = {0.0f, 0.0f, 0.0f, 0.0f};

    for (int base = blockIdx.x * 128; base < E; base += gridDim.x * 128) {
        const int m0 = base + w * 16;       // this wave's 16 rows
        int m = m0 + n16; if (m >= E) m = E - 1;
        const int sIdx = sendp[m], rIdx = recvp[m];

        f32x4 acc[8];

        // ---- embed GEMM1 (K=32; quad0 carries the 3 raw feats, sorted) ----
#pragma unroll
        for (int t = 0; t < 8; ++t) acc[t] = z;
        {
            bf16x8 a;
#pragma unroll
            for (int j = 0; j < 8; ++j) a[j] = (bf16)0.0f;
            if (quad == 0) {
                a[0] = (bf16)edges_s[(size_t)m * 3];
                a[1] = (bf16)edges_s[(size_t)m * 3 + 1];
                a[2] = (bf16)edges_s[(size_t)m * 3 + 2];
            }
            const bf16* bp = We0 + ((size_t)(quad * 128 + n16)) * 8;
#pragma unroll
            for (int t = 0; t < 8; ++t) {
                bf16x8 b = *(const bf16x8*)(bp + t * 128);
                acc[t] = __builtin_amdgcn_mfma_f32_16x16x32_bf16(a, b, acc[t], 0, 0, 0);
            }
        }
        // gelu + be0 -> Hw (A-layout)
#pragma unroll
        for (int t = 0; t < 8; ++t) {
            float bb = be0[t * 16 + n16];
#pragma unroll
            for (int r = 0; r < 4; ++r)
                Hw[(quad * 4 + r) * 136 + t * 16 + n16] = (bf16)gelu_t(acc[t][r] + bb);
        }
        // ---- embed GEMM2 (K=128, We1 from L2) -> eh0 (C-layout) ----
#pragma unroll
        for (int t = 0; t < 8; ++t) acc[t] = z;
#pragma unroll
        for (int kc = 0; kc < 128; kc += 32) {
            bf16x8 a = *(const bf16x8*)&Hw[n16 * 136 + kc + quad * 8];
            const bf16* bp = We1 + ((size_t)(((kc >> 3) + quad) * 128 + n16)) * 8;
#pragma unroll
            for (int t = 0; t < 8; ++t) {
                bf16x8 b = *(const bf16x8*)(bp + t * 128);
                acc[t] = __builtin_amdgcn_mfma_f32_16x16x32_bf16(a, b, acc[t], 0, 0, 0);
            }
        }
        // eh0 -> Hw (A-layout, bf16)
#pragma unroll
        for (int t = 0; t < 8; ++t) {
            float bb = be1[t * 16 + n16];
#pragma unroll
            for (int r = 0; r < 4; ++r)
                Hw[(quad * 4 + r) * 136 + t * 16 + n16] = (bf16)(acc[t][r] + bb);
        }
        bf16x8 a1[4];
#pragma unroll
        for (int c = 0; c < 4; ++c)
            a1[c] = *(const bf16x8*)&Hw[n16 * 136 + c * 32 + quad * 8];

        if constexpr (STEP == 1) {
            // eh1 = LN(eh0 + newe1); full row in lanes {n16,+16,+32,+48}
            float x[4][8];
            float sm = 0.0f, sq = 0.0f;
#pragma unroll
            for (int c = 0; c < 4; ++c) {
                bf16x8 ne = *(const bf16x8*)(newe + (size_t)m * 128 + c * 32 + quad * 8);
#pragma unroll
                for (int j = 0; j < 8; ++j) {
                    float v = (float)a1[c][j] + (float)ne[j];
                    x[c][j] = v; sm += v; sq += v * v;
                }
            }
            sm += __shfl_xor(sm, 16); sq += __shfl_xor(sq, 16);
            sm += __shfl_xor(sm, 32); sq += __shfl_xor(sq, 32);
            float mean = sm * (1.0f / 128.0f);
            float inv = rsqrtf(sq * (1.0f / 128.0f) - mean * mean + 1e-6f);
#pragma unroll
            for (int c = 0; c < 4; ++c)
#pragma unroll
                for (int j = 0; j < 8; ++j) {
                    int col = c * 32 + quad * 8 + j;
                    a1[c][j] = (bf16)((x[c][j] - mean) * inv * ln_s[col] + ln_b[col]);
                }
        }

        // ---- step GEMM1: K=384 = [eh | nh_s | nh_r], B from LDS (Ws0L) ----
#pragma unroll
        for (int t = 0; t < 8; ++t) acc[t] = z;
#pragma unroll
        for (int c = 0; c < 12; ++c) {
            const int k0 = (c & 3) * 32 + quad * 8;
            bf16x8 af;
            if (c < 4)      af = a1[c];
            else if (c < 8) af = *(const bf16x8*)(nh_b + (size_t)sIdx * 128 + k0);
            else            af = *(const bf16x8*)(nh_b + (size_t)rIdx * 128 + k0);
            const bf16* bp = Ws0L + ((c * 4 + quad) * 128 + n16) * 8;
#pragma unroll
            for (int t = 0; t < 8; ++t) {
                bf16x8 b = *(const bf16x8*)(bp + t * 128);
                acc[t] = __builtin_amdgcn_mfma_f32_16x16x32_bf16(af, b, acc[t], 0, 0, 0);
            }
        }
        // gelu + bs0 -> Hw
#pragma unroll
        for (int t = 0; t < 8; ++t) {
            float bb = bs0[t * 16 + n16];
#pragma unroll
            for (int r = 0; r < 4; ++r)
                Hw[(quad * 4 + r) * 136 + t * 16 + n16] = (bf16)gelu_t(acc[t][r] + bb);
        }
        // ---- step GEMM2 (K=128, Ws1 from L2) -> new_e ----
#pragma unroll
        for (int t = 0; t < 8; ++t) acc[t] = z;
#pragma unroll
        for (int kc = 0; kc < 128; kc += 32) {
            bf16x8 a = *(const bf16x8*)&Hw[n16 * 136 + kc + quad * 8];
            const bf16* bp = Ws1 + ((size_t)(((kc >> 3) + quad) * 128 + n16)) * 8;
#pragma unroll
            for (int t = 0; t < 8; ++t) {
                bf16x8 b = *(const bf16x8*)(bp + t * 128);
                acc[t] = __builtin_amdgcn_mfma_f32_16x16x32_bf16(a, b, acc[t], 0, 0, 0);
            }
        }
        // store new_e (guarded)
#pragma unroll
        for (int t = 0; t < 8; ++t) {
            float bb = bs1[t * 16 + n16];
#pragma unroll
            for (int r = 0; r < 4; ++r) {
                int row = m0 + quad * 4 + r;
                if (row < E)
                    newe[(size_t)row * 128 + t * 16 + n16] = (bf16)(acc[t][r] + bb);
            }
        }
    }
}

// ---------------- node kernels (r10 structure, unchanged) ----------------
// MODE 0: embed nodes  (K1=32, raw 7)  fp32 in  -> bf16 nh_b
// MODE 3: node update  (K1=256) bf16 nh_b + bf16 recvb -> bf16 nh_b in-place, skip+LN
// MODE 4: fused decode: bf16 nh_b -> GEMM1+gelu -> dot dec_W1[128,3] -> fp32 out[N,3]
template <int MODE, int K1, int RAWF>
__global__ __launch_bounds__(256, 5) void mlp2_kernel(
    const void* __restrict__ Araw0v, const bf16* __restrict__ Araw1b,
    const bf16* __restrict__ W0p, const float* __restrict__ b0,
    const bf16* __restrict__ W1p, const float* __restrict__ b1,
    const float* __restrict__ ln_s, const float* __restrict__ ln_b,
    void* out0v, int Mtotal)
{
    __shared__ __align__(16) bf16 Hsep[(MODE == 4) ? 1 : (4 * 16 * 136)];

    const int tid = threadIdx.x, lane = tid & 63, w = tid >> 6;
    const int n16 = lane & 15, quad = lane >> 4;
    const int m0 = blockIdx.x * 64;

    const float* Araw0f = (const float*)Araw0v;
    const bf16*  Araw0b = (const bf16*)Araw0v;
    float* out0f = (float*)out0v;
    bf16*  out0b = (bf16*)out0v;

    int m = m0 + w * 16 + n16;
    if (m >= Mtotal) m = Mtotal - 1;

    const f32x4 z = {0.0f, 0.0f, 0.0f, 0.0f};
    f32x4 acc[8];
#pragma unroll
    for (int t = 0; t < 8; ++t) acc[t] = z;

    // ---- GEMM1 ----
#pragma unroll
    for (int c = 0; c < K1 / 32; ++c) {
        const int k0 = c * 32 + quad * 8;
        bf16x8 a;
        if constexpr (MODE == 3) {
            if (c < 4) a = *(const bf16x8*)(Araw0b + (size_t)m * 128 + k0);
            else       a = *(const bf16x8*)(Araw1b + (size_t)m * 128 + (k0 - 128));
        } else if constexpr (MODE == 4) {
            a = *(const bf16x8*)(Araw0b + (size_t)m * 128 + k0);
        } else {  // MODE 0: RAWF raw features (<8), only quad 0 nonzero
#pragma unroll
            for (int j = 0; j < 8; ++j) a[j] = (bf16)0.0f;
            if (quad == 0) {
#pragma unroll
                for (int j = 0; j < RAWF; ++j)
                    a[j] = (bf16)Araw0f[(size_t)m * RAWF + j];
            }
        }
        const bf16* bp = W0p + ((size_t)((c * 4 + quad) * 128 + n16)) * 8;
#pragma unroll
        for (int t = 0; t < 8; ++t) {
            bf16x8 b = *(const bf16x8*)(bp + t * 128);
            acc[t] = __builtin_amdgcn_mfma_f32_16x16x32_bf16(a, b, acc[t], 0, 0, 0);
        }
    }

    float b0v[8];
#pragma unroll
    for (int t = 0; t < 8; ++t) b0v[t] = b0[t * 16 + n16];

    if constexpr (MODE == 4) {
        // fused decode: h = gelu(acc+b0); out[row,o] = sum_col h*W1[col,o] + b1[o]
        const float* W1d = ln_s;
        const float* b1d = ln_b;
        float p[4][3];
#pragma unroll
        for (int r = 0; r < 4; ++r) { p[r][0] = 0; p[r][1] = 0; p[r][2] = 0; }
#pragma unroll
        for (int t = 0; t < 8; ++t) {
            int col = t * 16 + n16;
            float w0 = W1d[col * 3 + 0], w1 = W1d[col * 3 + 1], w2 = W1d[col * 3 + 2];
#pragma unroll
            for (int r = 0; r < 4; ++r) {
                float h = gelu_t(acc[t][r] + b0v[t]);
                p[r][0] += h * w0; p[r][1] += h * w1; p[r][2] += h * w2;
            }
        }
#pragma unroll
        for (int mm = 1; mm < 16; mm <<= 1)
#pragma unroll
            for (int r = 0; r < 4; ++r) {
                p[r][0] += __shfl_xor(p[r][0], mm);
                p[r][1] += __shfl_xor(p[r][1], mm);
                p[r][2] += __shfl_xor(p[r][2], mm);
            }
        if (n16 < 3) {
            float bb = b1d[n16];
#pragma unroll
            for (int r = 0; r < 4; ++r) {
                int row = m0 + w * 16 + quad * 4 + r;
                if (row < Mtotal)
                    out0f[(size_t)row * 3 + n16] = p[r][n16] + bb;
            }
        }
        return;
    }

    // hidden -> A-layout via wave-private LDS slab
    bf16* Hw = &Hsep[w * 16 * 136];
#pragma unroll
    for (int t = 0; t < 8; ++t)
#pragma unroll
        for (int r = 0; r < 4; ++r)
            Hw[(quad * 4 + r) * 136 + t * 16 + n16] = (bf16)gelu_t(acc[t][r] + b0v[t]);

    // ---- GEMM2 (K=128) ----
#pragma unroll
    for (int t = 0; t < 8; ++t) acc[t] = z;
#pragma unroll
    for (int kc = 0; kc < 128; kc += 32) {
        bf16x8 a = *(const bf16x8*)&Hw[n16 * 136 + kc + quad * 8];
        const bf16* bp = W1p + ((size_t)(((kc >> 3) + quad) * 128 + n16)) * 8;
#pragma unroll
        for (int t = 0; t < 8; ++t) {
            bf16x8 b = *(const bf16x8*)(bp + t * 128);
            acc[t] = __builtin_amdgcn_mfma_f32_16x16x32_bf16(a, b, acc[t], 0, 0, 0);
        }
    }

    if constexpr (MODE == 0) {  // embed nodes: plain bf16 store
#pragma unroll
        for (int t = 0; t < 8; ++t) {
            float b1v = b1[t * 16 + n16];
#pragma unroll
            for (int r = 0; r < 4; ++r) {
                int row = m0 + w * 16 + quad * 4 + r;
                if (row < Mtotal)
                    out0b[(size_t)row * 128 + t * 16 + n16] = (bf16)(acc[t][r] + b1v);
            }
        }
        return;
    }

    // ---- MODE 3 epilogue: skip + LayerNorm ----
    float b1v[8], scl[8], bia[8];
#pragma unroll
    for (int t = 0; t < 8; ++t) {
        int col = t * 16 + n16;
        b1v[t] = b1[col]; scl[t] = ln_s[col]; bia[t] = ln_b[col];
    }
    int rowg[4];
#pragma unroll
    for (int r = 0; r < 4; ++r) rowg[r] = m0 + w * 16 + quad * 4 + r;
    float x[8][4];
    float sm[4] = {0, 0, 0, 0}, sq[4] = {0, 0, 0, 0};
#pragma unroll
    for (int t = 0; t < 8; ++t) {
        int col = t * 16 + n16;
#pragma unroll
        for (int r = 0; r < 4; ++r) {
            bool ok = rowg[r] < Mtotal;
            float v = acc[t][r] + b1v[t];
            float old = ok ? (float)Araw0b[(size_t)rowg[r] * 128 + col] : 0.0f;
            float xx = old + v;
            x[t][r] = xx; sm[r] += xx; sq[r] += xx * xx;
        }
    }
#pragma unroll
    for (int mm = 1; mm < 16; mm <<= 1)
#pragma unroll
        for (int r = 0; r < 4; ++r) {
            sm[r] += __shfl_xor(sm[r], mm);
            sq[r] += __shfl_xor(sq[r], mm);
        }
    float mean[4], inv[4];
#pragma unroll
    for (int r = 0; r < 4; ++r) {
        mean[r] = sm[r] * (1.0f / 128.0f);
        float var = sq[r] * (1.0f / 128.0f) - mean[r] * mean[r];
        inv[r] = rsqrtf(var + 1e-6f);
    }
#pragma unroll
    for (int t = 0; t < 8; ++t)
#pragma unroll
        for (int r = 0; r < 4; ++r)
            if (rowg[r] < Mtotal)
                out0b[(size_t)rowg[r] * 128 + t * 16 + n16] =
                    (bf16)((x[t][r] - mean[r]) * inv[r] * scl[t] + bia[t]);
}

extern "C" void kernel_launch(void* const* d_in, const int* in_sizes, int n_in,
                              void* d_out, int out_size, void* d_ws, size_t ws_size,
                              hipStream_t stream) {
    const float* nodes   = (const float*)d_in[0];
    const float* edges   = (const float*)d_in[1];
    const float* glob    = (const float*)d_in[2];
    const int*   senders = (const int*)d_in[3];
    const int*   recvrs  = (const int*)d_in[4];
    const float* ne_W0 = (const float*)d_in[5],  *ne_b0 = (const float*)d_in[6];
    const float* ne_W1 = (const float*)d_in[7],  *ne_b1 = (const float*)d_in[8];
    const float* ee_W0 = (const float*)d_in[9],  *ee_b0 = (const float*)d_in[10];
    const float* ee_W1 = (const float*)d_in[11], *ee_b1 = (const float*)d_in[12];
    const float* eu_W0 = (const float*)d_in[13], *eu_b0 = (const float*)d_in[14];
    const float* eu_W1 = (const float*)d_in[15], *eu_b1 = (const float*)d_in[16];
    const float* nu_W0 = (const float*)d_in[17], *nu_b0 = (const float*)d_in[18];
    const float* nu_W1 = (const float*)d_in[19], *nu_b1 = (const float*)d_in[20];
    const float* ln_s  = (const float*)d_in[21], *ln_b  = (const float*)d_in[22];
    const float* dc_W0 = (const float*)d_in[23], *dc_b0 = (const float*)d_in[24];
    const float* dc_W1 = (const float*)d_in[25], *dc_b1 = (const float*)d_in[26];

    const int N = 50000, E = 500000;

    const int KD[13] = {32, 128, 32, 128, 384, 384, 128, 128, 256, 256, 128, 128, 128};
    const int KC[13] = {7, 128, 3, 128, 384, 384, 128, 128, 256, 256, 128, 128, 128};
    int pre[14]; pre[0] = 0;
    for (int i = 0; i < 13; ++i) pre[i + 1] = pre[i] + KD[i] * 128;
    const int totalPack = pre[13];

    char* ws = (char*)d_ws;
    size_t off = 0;
    auto alloc = [&](size_t bytes) -> char* {
        char* p = ws + off;
        off = (off + bytes + 255) & ~(size_t)255;
        return p;
    };
    bf16*  Wp      = (bf16*)alloc((size_t)totalPack * 2);
    float* b0e_eu  = (float*)alloc(2 * 128 * 4);
    float* b0e_nu  = (float*)alloc(2 * 128 * 4);
    bf16*  nh_b    = (bf16*)alloc((size_t)N * 128 * 2);      // 12.8 MB
    bf16*  recvb   = (bf16*)alloc((size_t)N * 128 * 2);      // 12.8 MB
    bf16*  newe    = (bf16*)alloc((size_t)E * 128 * 2);      // 128 MB
    int*   deg     = (int*)alloc((size_t)N * 4);
    int*   cursor  = (int*)alloc((size_t)N * 4);
    int*   bsum    = (int*)alloc(256 * 4);
    float* edges_s = (float*)alloc((size_t)E * 3 * 4);       // 6 MB sorted raw feats
    int*   sendp   = (int*)alloc((size_t)E * 4);
    int*   recvp   = (int*)alloc((size_t)E * 4);
    // total ~164 MB (proven-good envelope)

    if (off > ws_size) return;  // clean diagnostic instead of OOB fault

    PackArgs pa;
    const float* srcs[13] = {
        ne_W0, ne_W1, ee_W0, ee_W1,
        eu_W0, eu_W0 + (size_t)386 * 128,
        eu_W1, eu_W1 + (size_t)128 * 128,
        nu_W0, nu_W0 + (size_t)258 * 128,
        nu_W1, nu_W1 + (size_t)128 * 128,
        dc_W0};
    for (int i = 0; i < 13; ++i) { pa.d[i].src = srcs[i]; pa.d[i].Kcopy = KC[i]; pa.d[i].dstOff = pre[i]; }

    pack_all_kernel<<<(totalPack + 255) / 256, 256, 0, stream>>>(pa, Wp, totalPack);
    fold_bias_kernel<<<1, 128, 0, stream>>>(glob, eu_W0, eu_b0, nu_W0, nu_b0, b0e_eu, b0e_nu);

    // ---- receiver counting-sort ----
    const int gEdge = (E + 255) / 256;
    const int nb = (N + 255) / 256;
    zero_kernel<<<(N / 4 + 255) / 256, 256, 0, stream>>>((float4*)deg, N / 4);
    hist_kernel<<<gEdge, 256, 0, stream>>>(recvrs, deg, E);
    scan_part_kernel<<<nb, 256, 0, stream>>>(deg, cursor, bsum, N);
    scan_top_kernel<<<1, 256, 0, stream>>>(bsum, nb);
    scan_add_kernel<<<nb, 256, 0, stream>>>(cursor, bsum, N);
    scatter_kernel<<<gEdge, 256, 0, stream>>>(senders, recvrs, edges, cursor,
                                              edges_s, sendp, recvp, E);
    // cursor now holds CSR end-offsets

    const int gN = (N + 63) / 64;
    mlp2_kernel<0, 32, 7><<<gN, 256, 0, stream>>>(
        nodes, nullptr, Wp + pre[0], ne_b0, Wp + pre[1], ne_b1,
        nullptr, nullptr, nh_b, N);

    for (int s = 0; s < 2; ++s) {
        if (s == 0)
            edge_kernel<0><<<256, 512, 0, stream>>>(
                edges_s, sendp, recvp, nh_b, newe,
                Wp + pre[2], ee_b0, Wp + pre[3], ee_b1, ln_s, ln_b,
                Wp + pre[4], b0e_eu, Wp + pre[6], eu_b1, E);
        else
            edge_kernel<1><<<256, 512, 0, stream>>>(
                edges_s, sendp, recvp, nh_b, newe,
                Wp + pre[2], ee_b0, Wp + pre[3], ee_b1, ln_s, ln_b,
                Wp + pre[5], b0e_eu + 128, Wp + pre[7], eu_b1 + 128, E);
        segsum_kernel<<<(N + 3) / 4, 256, 0, stream>>>(newe, cursor, recvb, N);
        mlp2_kernel<3, 256, 0><<<gN, 256, 0, stream>>>(
            nh_b, recvb, Wp + pre[8 + s], b0e_nu + s * 128,
            Wp + pre[10 + s], nu_b1 + s * 128, ln_s, ln_b, nh_b, N);
    }

    mlp2_kernel<4, 128, 0><<<gN, 256, 0, stream>>>(
        nh_b, nullptr, Wp + pre[12], dc_b0, nullptr, nullptr,
        dc_W1, dc_b1, d_out, N);
}

// Round 12
// 827.521 us; speedup vs baseline: 1.5423x; 1.5423x over previous
//
#include <hip/hip_runtime.h>
#include <hip/hip_bf16.h>

// GraphConvNet on MI355X — round 12: r10 + depth-1 double-buffered B-fragment
// prefetch in the edge kernel.
// r11 (persistent/weights-in-LDS) regressed 2.2x: 133KB LDS -> 1 block/CU and
// grid-stride killed sorted-gather L2 locality (FETCH 146->990MB). Reverted.
// Plateau theory v3: (256,5)'s ~102-reg cap leaves room for exactly ONE chunk
// of B (32 VGPR) -> every one of ~21 GEMM chunks pays a full ~200-400cyc L2
// round trip that 8 MFMAs (~50cyc) can't hide, and the compiler can't hoist
// across chunks with zero spare regs. Fix: manual prefetch of chunk c+1's B
// (and gathered A) during chunk c's MFMAs; __launch_bounds__(256,3) gives the
// allocator ~170 regs (est. use ~135). Occupancy 52->~37% (44 vs 52 was flat).
// Everything else byte-identical to r10.
//
// MFMA fragment facts (guide §3, m89/m91/m120 verified):
//   A: lane holds A[m=lane&15][k=(lane>>4)*8+j]
//   B: lane holds B[k=(lane>>4)*8+j][n=lane&15]
//   C/D: lane reg r holds C[row=(lane>>4)*4+r][col=lane&15]

typedef __bf16 bf16;
typedef __attribute__((ext_vector_type(8))) __bf16 bf16x8;
typedef __attribute__((ext_vector_type(2))) __bf16 bf16x2;
typedef __attribute__((ext_vector_type(4))) float f32x4;

__device__ __forceinline__ float gelu_t(float x) {
    // exact identity: 0.5x(1+tanh(u)) == x*sigmoid(2u) = x/(1+exp(-2u))
    const float kn0 = -1.5957691216057308f;   // -2*sqrt(2/pi)
    const float kn1 = -0.07135481627159855f;  // -2*sqrt(2/pi)*0.044715
    float x2 = x * x;
    float w = x * __builtin_fmaf(kn1, x2, kn0);
    float e = __expf(w);
    return __fdividef(x, 1.0f + e);
}

// ---------------- weight packing: [K,128] fp32 -> bf16 [K/8][128][8] ----------------
struct PackDesc { const float* src; int Kcopy; int dstOff; };
struct PackArgs { PackDesc d[13]; };

__global__ __launch_bounds__(256) void pack_all_kernel(PackArgs pa, bf16* dst, int total) {
    int i = blockIdx.x * 256 + threadIdx.x;
    if (i >= total) return;
    int s = 0;
#pragma unroll
    for (int j = 1; j < 13; ++j) if (i >= pa.d[j].dstOff) s = j;
    int local = i - pa.d[s].dstOff;
    int k = local >> 7, n = local & 127;
    float v = (k < pa.d[s].Kcopy) ? pa.d[s].src[(size_t)k * 128 + n] : 0.0f;
    dst[pa.d[s].dstOff + ((k >> 3) * 128 + n) * 8 + (k & 7)] = (bf16)v;
}

__global__ void fold_bias_kernel(const float* g, const float* euW0, const float* eub0,
                                 const float* nuW0, const float* nub0,
                                 float* eu_eff, float* nu_eff) {
    int t = threadIdx.x;
    if (t < 128) {
        float g0 = g[0], g1 = g[1];
#pragma unroll
        for (int s = 0; s < 2; ++s) {
            eu_eff[s * 128 + t] = eub0[s * 128 + t]
                + g0 * euW0[((size_t)s * 386 + 384) * 128 + t]
                + g1 * euW0[((size_t)s * 386 + 385) * 128 + t];
            nu_eff[s * 128 + t] = nub0[s * 128 + t]
                + g0 * nuW0[((size_t)s * 258 + 256) * 128 + t]
                + g1 * nuW0[((size_t)s * 258 + 257) * 128 + t];
        }
    }
}

__global__ __launch_bounds__(256) void zero_kernel(float4* p, int n4) {
    int i = blockIdx.x * 256 + threadIdx.x;
    if (i < n4) p[i] = float4{0.0f, 0.0f, 0.0f, 0.0f};
}

// ---------------- receiver-sort (counting sort) ----------------
__global__ __launch_bounds__(256) void hist_kernel(const int* __restrict__ recv,
                                                   int* __restrict__ deg, int E) {
    int e = blockIdx.x * 256 + threadIdx.x;
    if (e < E) atomicAdd(&deg[recv[e]], 1);
}

__global__ __launch_bounds__(256) void scan_part_kernel(const int* __restrict__ deg,
                                                        int* __restrict__ cursor,
                                                        int* __restrict__ bsum, int n) {
    __shared__ int tmp[256];
    int t = threadIdx.x, g = blockIdx.x * 256 + t;
    int v = (g < n) ? deg[g] : 0;
    tmp[t] = v; __syncthreads();
#pragma unroll
    for (int o = 1; o < 256; o <<= 1) {
        int x = (t >= o) ? tmp[t - o] : 0;
        __syncthreads();
        tmp[t] += x;
        __syncthreads();
    }
    if (g < n) cursor[g] = tmp[t] - v;
    if (t == 255) bsum[blockIdx.x] = tmp[255];
}

__global__ void scan_top_kernel(int* bsum, int nb) {  // single block, nb<=256
    __shared__ int tmp[256];
    int t = threadIdx.x;
    int v = (t < nb) ? bsum[t] : 0;
    tmp[t] = v; __syncthreads();
#pragma unroll
    for (int o = 1; o < 256; o <<= 1) {
        int x = (t >= o) ? tmp[t - o] : 0;
        __syncthreads();
        tmp[t] += x;
        __syncthreads();
    }
    if (t < nb) bsum[t] = tmp[t] - v;
}

__global__ __launch_bounds__(256) void scan_add_kernel(int* __restrict__ cursor,
                                                       const int* __restrict__ bsum, int n) {
    int g = blockIdx.x * 256 + threadIdx.x;
    if (g < n) cursor[g] += bsum[blockIdx.x];
}

// scatter: also pre-sorts raw edge features (edges_s[pos] = edges[e])
__global__ __launch_bounds__(256) void scatter_kernel(
    const int* __restrict__ send, const int* __restrict__ recv,
    const float* __restrict__ edges_raw, int* __restrict__ cursor,
    float* __restrict__ edges_s, int* __restrict__ sendp, int* __restrict__ recvp, int E) {
    int e = blockIdx.x * 256 + threadIdx.x;
    if (e >= E) return;
    int r = recv[e];
    int pos = atomicAdd(&cursor[r], 1);
    sendp[pos] = send[e]; recvp[pos] = r;
    edges_s[(size_t)pos * 3]     = edges_raw[(size_t)e * 3];
    edges_s[(size_t)pos * 3 + 1] = edges_raw[(size_t)e * 3 + 1];
    edges_s[(size_t)pos * 3 + 2] = edges_raw[(size_t)e * 3 + 2];
}
// after scatter: cursor[i] == end offset of node i's segment (CSR row end)

// ---------------- segment-sum: recvb[i] = sum of newe rows in [start,end) ----------------
__global__ __launch_bounds__(256) void segsum_kernel(const bf16* __restrict__ newe,
                                                     const int* __restrict__ endoff,
                                                     bf16* __restrict__ recvb, int N) {
    int node = blockIdx.x * 4 + (threadIdx.x >> 6);
    if (node >= N) return;
    int lane = threadIdx.x & 63;
    int start = (node == 0) ? 0 : endoff[node - 1];
    int end = endoff[node];
    float s0 = 0.0f, s1 = 0.0f, t0 = 0.0f, t1 = 0.0f;
    int e = start;
    for (; e + 1 < end; e += 2) {
        bf16x2 v = *(const bf16x2*)(newe + (size_t)e * 128 + lane * 2);
        bf16x2 u = *(const bf16x2*)(newe + (size_t)(e + 1) * 128 + lane * 2);
        s0 += (float)v[0]; s1 += (float)v[1];
        t0 += (float)u[0]; t1 += (float)u[1];
    }
    if (e < end) {
        bf16x2 v = *(const bf16x2*)(newe + (size_t)e * 128 + lane * 2);
        s0 += (float)v[0]; s1 += (float)v[1];
    }
    bf16x2 o; o[0] = (bf16)(s0 + t0); o[1] = (bf16)(s1 + t1);
    *(bf16x2*)(recvb + (size_t)node * 128 + lane * 2) = o;
}

// ---------------- edge megakernel: embed(recompute) [+LN skip] + step MLP ----------------
// STEP 0: new_e1 = MLP_s0(concat(eh0, nh_s, nh_r)+g)        ; newe <- new_e1
// STEP 1: eh1 = LN(eh0+newe1); new_e2 = MLP_s1(concat(...)) ; newe <- new_e2 (in-place)
// Each wave owns 16 edge rows end-to-end; barrier-free; no atomics.
// NEW r12: depth-1 double-buffered B (and gathered A) across GEMM chunks.
template <int STEP>
__global__ __launch_bounds__(256, 3) void edge_kernel(
    const float* __restrict__ edges_s,
    const int* __restrict__ sendp, const int* __restrict__ recvp,
    const bf16* __restrict__ nh_b, bf16* __restrict__ newe,
    const bf16* __restrict__ We0, const float* __restrict__ be0,
    const bf16* __restrict__ We1, const float* __restrict__ be1,
    const float* __restrict__ ln_s, const float* __restrict__ ln_b,
    const bf16* __restrict__ Ws0, const float* __restrict__ bs0,
    const bf16* __restrict__ Ws1, const float* __restrict__ bs1,
    int E)
{
    __shared__ __align__(16) bf16 Hsep[4 * 16 * 136];
    const int tid = threadIdx.x, lane = tid & 63, w = tid >> 6;
    const int n16 = lane & 15, quad = lane >> 4;
    const int m0 = blockIdx.x * 64;
    int m = m0 + w * 16 + n16; if (m >= E) m = E - 1;
    const int sIdx = sendp[m], rIdx = recvp[m];

    bf16* Hw = &Hsep[w * 16 * 136];
    const f32x4 z = {0.0f, 0.0f, 0.0f, 0.0f};
    f32x4 acc[8];
    bf16x8 bq[8], bq2[8];

    // ---- embed GEMM1 (K=32; single chunk; quad0 carries the 3 raw feats) ----
#pragma unroll
    for (int t = 0; t < 8; ++t) acc[t] = z;
    {
        bf16x8 a;
#pragma unroll
        for (int j = 0; j < 8; ++j) a[j] = (bf16)0.0f;
        if (quad == 0) {
            a[0] = (bf16)edges_s[(size_t)m * 3];
            a[1] = (bf16)edges_s[(size_t)m * 3 + 1];
            a[2] = (bf16)edges_s[(size_t)m * 3 + 2];
        }
        const bf16* bp = We0 + ((size_t)(quad * 128 + n16)) * 8;
#pragma unroll
        for (int t = 0; t < 8; ++t) {
            bf16x8 b = *(const bf16x8*)(bp + t * 128);
            acc[t] = __builtin_amdgcn_mfma_f32_16x16x32_bf16(a, b, acc[t], 0, 0, 0);
        }
    }
    // gelu + be0 -> Hw (A-layout)
#pragma unroll
    for (int t = 0; t < 8; ++t) {
        float bb = be0[t * 16 + n16];
#pragma unroll
        for (int r = 0; r < 4; ++r)
            Hw[(quad * 4 + r) * 136 + t * 16 + n16] = (bf16)gelu_t(acc[t][r] + bb);
    }

    // ---- embed GEMM2 (K=128, 4 chunks, B double-buffered) -> eh0 (C-layout) ----
#pragma unroll
    for (int t = 0; t < 8; ++t) acc[t] = z;
    {
        const bf16* bp0 = We1 + ((size_t)(quad * 128 + n16)) * 8;
#pragma unroll
        for (int t = 0; t < 8; ++t) bq[t] = *(const bf16x8*)(bp0 + t * 128);
    }
#pragma unroll
    for (int c = 0; c < 4; ++c) {
        if (c + 1 < 4) {
            const bf16* bp2 = We1 + ((size_t)(((c + 1) * 4 + quad) * 128 + n16)) * 8;
#pragma unroll
            for (int t = 0; t < 8; ++t) bq2[t] = *(const bf16x8*)(bp2 + t * 128);
        }
        bf16x8 a = *(const bf16x8*)&Hw[n16 * 136 + c * 32 + quad * 8];
#pragma unroll
        for (int t = 0; t < 8; ++t)
            acc[t] = __builtin_amdgcn_mfma_f32_16x16x32_bf16(a, bq[t], acc[t], 0, 0, 0);
#pragma unroll
        for (int t = 0; t < 8; ++t) bq[t] = bq2[t];
    }
    // eh0 -> Hw (A-layout, bf16)
#pragma unroll
    for (int t = 0; t < 8; ++t) {
        float bb = be1[t * 16 + n16];
#pragma unroll
        for (int r = 0; r < 4; ++r)
            Hw[(quad * 4 + r) * 136 + t * 16 + n16] = (bf16)(acc[t][r] + bb);
    }
    bf16x8 a1[4];
#pragma unroll
    for (int c = 0; c < 4; ++c)
        a1[c] = *(const bf16x8*)&Hw[n16 * 136 + c * 32 + quad * 8];

    if constexpr (STEP == 1) {
        // eh1 = LN(eh0 + newe1) on A-fragments; full row in lanes {n16,+16,+32,+48}
        float x[4][8];
        float sm = 0.0f, sq = 0.0f;
#pragma unroll
        for (int c = 0; c < 4; ++c) {
            bf16x8 ne = *(const bf16x8*)(newe + (size_t)m * 128 + c * 32 + quad * 8);
#pragma unroll
            for (int j = 0; j < 8; ++j) {
                float v = (float)a1[c][j] + (float)ne[j];
                x[c][j] = v; sm += v; sq += v * v;
            }
        }
        sm += __shfl_xor(sm, 16); sq += __shfl_xor(sq, 16);
        sm += __shfl_xor(sm, 32); sq += __shfl_xor(sq, 32);
        float mean = sm * (1.0f / 128.0f);
        float inv = rsqrtf(sq * (1.0f / 128.0f) - mean * mean + 1e-6f);
#pragma unroll
        for (int c = 0; c < 4; ++c)
#pragma unroll
            for (int j = 0; j < 8; ++j) {
                int col = c * 32 + quad * 8 + j;
                a1[c][j] = (bf16)((x[c][j] - mean) * inv * ln_s[col] + ln_b[col]);
            }
    }

    // ---- step GEMM1: K=384, 12 chunks = [eh | nh_s | nh_r]; A+B double-buffered ----
#pragma unroll
    for (int t = 0; t < 8; ++t) acc[t] = z;
    {
        const bf16* bp0 = Ws0 + ((size_t)(quad * 128 + n16)) * 8;
#pragma unroll
        for (int t = 0; t < 8; ++t) bq[t] = *(const bf16x8*)(bp0 + t * 128);
    }
    bf16x8 af = a1[0], af2;
#pragma unroll
    for (int c = 0; c < 12; ++c) {
        if (c + 1 < 12) {
            const bf16* bp2 = Ws0 + ((size_t)(((c + 1) * 4 + quad) * 128 + n16)) * 8;
#pragma unroll
            for (int t = 0; t < 8; ++t) bq2[t] = *(const bf16x8*)(bp2 + t * 128);
            const int k0n = ((c + 1) & 3) * 32 + quad * 8;
            if (c + 1 < 4)      af2 = a1[c + 1];
            else if (c + 1 < 8) af2 = *(const bf16x8*)(nh_b + (size_t)sIdx * 128 + k0n);
            else                af2 = *(const bf16x8*)(nh_b + (size_t)rIdx * 128 + k0n);
        }
#pragma unroll
        for (int t = 0; t < 8; ++t)
            acc[t] = __builtin_amdgcn_mfma_f32_16x16x32_bf16(af, bq[t], acc[t], 0, 0, 0);
        af = af2;
#pragma unroll
        for (int t = 0; t < 8; ++t) bq[t] = bq2[t];
    }
    // gelu + bs0 -> Hw
#pragma unroll
    for (int t = 0; t < 8; ++t) {
        float bb = bs0[t * 16 + n16];
#pragma unroll
        for (int r = 0; r < 4; ++r)
            Hw[(quad * 4 + r) * 136 + t * 16 + n16] = (bf16)gelu_t(acc[t][r] + bb);
    }
    // ---- step GEMM2 (K=128, 4 chunks, B double-buffered) -> new_e ----
#pragma unroll
    for (int t = 0; t < 8; ++t) acc[t] = z;
    {
        const bf16* bp0 = Ws1 + ((size_t)(quad * 128 + n16)) * 8;
#pragma unroll
        for (int t = 0; t < 8; ++t) bq[t] = *(const bf16x8*)(bp0 + t * 128);
    }
#pragma unroll
    for (int c = 0; c < 4; ++c) {
        if (c + 1 < 4) {
            const bf16* bp2 = Ws1 + ((size_t)(((c + 1) * 4 + quad) * 128 + n16)) * 8;
#pragma unroll
            for (int t = 0; t < 8; ++t) bq2[t] = *(const bf16x8*)(bp2 + t * 128);
        }
        bf16x8 a = *(const bf16x8*)&Hw[n16 * 136 + c * 32 + quad * 8];
#pragma unroll
        for (int t = 0; t < 8; ++t)
            acc[t] = __builtin_amdgcn_mfma_f32_16x16x32_bf16(a, bq[t], acc[t], 0, 0, 0);
#pragma unroll
        for (int t = 0; t < 8; ++t) bq[t] = bq2[t];
    }
    // store new_e (guarded)
#pragma unroll
    for (int t = 0; t < 8; ++t) {
        float bb = bs1[t * 16 + n16];
#pragma unroll
        for (int r = 0; r < 4; ++r) {
            int row = m0 + w * 16 + quad * 4 + r;
            if (row < E)
                newe[(size_t)row * 128 + t * 16 + n16] = (bf16)(acc[t][r] + bb);
        }
    }
}

// ---------------- node kernels (r10 structure, unchanged) ----------------
// MODE 0: embed nodes  (K1=32, raw 7)  fp32 in  -> bf16 nh_b
// MODE 3: node update  (K1=256) bf16 nh_b + bf16 recvb -> bf16 nh_b in-place, skip+LN
// MODE 4: fused decode: bf16 nh_b -> GEMM1+gelu -> dot dec_W1[128,3] -> fp32 out[N,3]
template <int MODE, int K1, int RAWF>
__global__ __launch_bounds__(256, 5) void mlp2_kernel(
    const void* __restrict__ Araw0v, const bf16* __restrict__ Araw1b,
    const bf16* __restrict__ W0p, const float* __restrict__ b0,
    const bf16* __restrict__ W1p, const float* __restrict__ b1,
    const float* __restrict__ ln_s, const float* __restrict__ ln_b,
    void* out0v, int Mtotal)
{
    __shared__ __align__(16) bf16 Hsep[(MODE == 4) ? 1 : (4 * 16 * 136)];

    const int tid = threadIdx.x, lane = tid & 63, w = tid >> 6;
    const int n16 = lane & 15, quad = lane >> 4;
    const int m0 = blockIdx.x * 64;

    const float* Araw0f = (const float*)Araw0v;
    const bf16*  Araw0b = (const bf16*)Araw0v;
    float* out0f = (float*)out0v;
    bf16*  out0b = (bf16*)out0v;

    int m = m0 + w * 16 + n16;
    if (m >= Mtotal) m = Mtotal - 1;

    const f32x4 z = {0.0f, 0.0f, 0.0f, 0.0f};
    f32x4 acc[8];
#pragma unroll
    for (int t = 0; t < 8; ++t) acc[t] = z;

    // ---- GEMM1 ----
#pragma unroll
    for (int c = 0; c < K1 / 32; ++c) {
        const int k0 = c * 32 + quad * 8;
        bf16x8 a;
        if constexpr (MODE == 3) {
            if (c < 4) a = *(const bf16x8*)(Araw0b + (size_t)m * 128 + k0);
            else       a = *(const bf16x8*)(Araw1b + (size_t)m * 128 + (k0 - 128));
        } else if constexpr (MODE == 4) {
            a = *(const bf16x8*)(Araw0b + (size_t)m * 128 + k0);
        } else {  // MODE 0: RAWF raw features (<8), only quad 0 nonzero
#pragma unroll
            for (int j = 0; j < 8; ++j) a[j] = (bf16)0.0f;
            if (quad == 0) {
#pragma unroll
                for (int j = 0; j < RAWF; ++j)
                    a[j] = (bf16)Araw0f[(size_t)m * RAWF + j];
            }
        }
        const bf16* bp = W0p + ((size_t)((c * 4 + quad) * 128 + n16)) * 8;
#pragma unroll
        for (int t = 0; t < 8; ++t) {
            bf16x8 b = *(const bf16x8*)(bp + t * 128);
            acc[t] = __builtin_amdgcn_mfma_f32_16x16x32_bf16(a, b, acc[t], 0, 0, 0);
        }
    }

    float b0v[8];
#pragma unroll
    for (int t = 0; t < 8; ++t) b0v[t] = b0[t * 16 + n16];

    if constexpr (MODE == 4) {
        // fused decode: h = gelu(acc+b0); out[row,o] = sum_col h*W1[col,o] + b1[o]
        const float* W1d = ln_s;
        const float* b1d = ln_b;
        float p[4][3];
#pragma unroll
        for (int r = 0; r < 4; ++r) { p[r][0] = 0; p[r][1] = 0; p[r][2] = 0; }
#pragma unroll
        for (int t = 0; t < 8; ++t) {
            int col = t * 16 + n16;
            float w0 = W1d[col * 3 + 0], w1 = W1d[col * 3 + 1], w2 = W1d[col * 3 + 2];
#pragma unroll
            for (int r = 0; r < 4; ++r) {
                float h = gelu_t(acc[t][r] + b0v[t]);
                p[r][0] += h * w0; p[r][1] += h * w1; p[r][2] += h * w2;
            }
        }
#pragma unroll
        for (int mm = 1; mm < 16; mm <<= 1)
#pragma unroll
            for (int r = 0; r < 4; ++r) {
                p[r][0] += __shfl_xor(p[r][0], mm);
                p[r][1] += __shfl_xor(p[r][1], mm);
                p[r][2] += __shfl_xor(p[r][2], mm);
            }
        if (n16 < 3) {
            float bb = b1d[n16];
#pragma unroll
            for (int r = 0; r < 4; ++r) {
                int row = m0 + w * 16 + quad * 4 + r;
                if (row < Mtotal)
                    out0f[(size_t)row * 3 + n16] = p[r][n16] + bb;
            }
        }
        return;
    }

    // hidden -> A-layout via wave-private LDS slab
    bf16* Hw = &Hsep[w * 16 * 136];
#pragma unroll
    for (int t = 0; t < 8; ++t)
#pragma unroll
        for (int r = 0; r < 4; ++r)
            Hw[(quad * 4 + r) * 136 + t * 16 + n16] = (bf16)gelu_t(acc[t][r] + b0v[t]);

    // ---- GEMM2 (K=128) ----
#pragma unroll
    for (int t = 0; t < 8; ++t) acc[t] = z;
#pragma unroll
    for (int kc = 0; kc < 128; kc += 32) {
        bf16x8 a = *(const bf16x8*)&Hw[n16 * 136 + kc + quad * 8];
        const bf16* bp = W1p + ((size_t)(((kc >> 3) + quad) * 128 + n16)) * 8;
#pragma unroll
        for (int t = 0; t < 8; ++t) {
            bf16x8 b = *(const bf16x8*)(bp + t * 128);
            acc[t] = __builtin_amdgcn_mfma_f32_16x16x32_bf16(a, b, acc[t], 0, 0, 0);
        }
    }

    if constexpr (MODE == 0) {  // embed nodes: plain bf16 store
#pragma unroll
        for (int t = 0; t < 8; ++t) {
            float b1v = b1[t * 16 + n16];
#pragma unroll
            for (int r = 0; r < 4; ++r) {
                int row = m0 + w * 16 + quad * 4 + r;
                if (row < Mtotal)
                    out0b[(size_t)row * 128 + t * 16 + n16] = (bf16)(acc[t][r] + b1v);
            }
        }
        return;
    }

    // ---- MODE 3 epilogue: skip + LayerNorm ----
    float b1v[8], scl[8], bia[8];
#pragma unroll
    for (int t = 0; t < 8; ++t) {
        int col = t * 16 + n16;
        b1v[t] = b1[col]; scl[t] = ln_s[col]; bia[t] = ln_b[col];
    }
    int rowg[4];
#pragma unroll
    for (int r = 0; r < 4; ++r) rowg[r] = m0 + w * 16 + quad * 4 + r;
    float x[8][4];
    float sm[4] = {0, 0, 0, 0}, sq[4] = {0, 0, 0, 0};
#pragma unroll
    for (int t = 0; t < 8; ++t) {
        int col = t * 16 + n16;
#pragma unroll
        for (int r = 0; r < 4; ++r) {
            bool ok = rowg[r] < Mtotal;
            float v = acc[t][r] + b1v[t];
            float old = ok ? (float)Araw0b[(size_t)rowg[r] * 128 + col] : 0.0f;
            float xx = old + v;
            x[t][r] = xx; sm[r] += xx; sq[r] += xx * xx;
        }
    }
#pragma unroll
    for (int mm = 1; mm < 16; mm <<= 1)
#pragma unroll
        for (int r = 0; r < 4; ++r) {
            sm[r] += __shfl_xor(sm[r], mm);
            sq[r] += __shfl_xor(sq[r], mm);
        }
    float mean[4], inv[4];
#pragma unroll
    for (int r = 0; r < 4; ++r) {
        mean[r] = sm[r] * (1.0f / 128.0f);
        float var = sq[r] * (1.0f / 128.0f) - mean[r] * mean[r];
        inv[r] = rsqrtf(var + 1e-6f);
    }
#pragma unroll
    for (int t = 0; t < 8; ++t)
#pragma unroll
        for (int r = 0; r < 4; ++r)
            if (rowg[r] < Mtotal)
                out0b[(size_t)rowg[r] * 128 + t * 16 + n16] =
                    (bf16)((x[t][r] - mean[r]) * inv[r] * scl[t] + bia[t]);
}

extern "C" void kernel_launch(void* const* d_in, const int* in_sizes, int n_in,
                              void* d_out, int out_size, void* d_ws, size_t ws_size,
                              hipStream_t stream) {
    const float* nodes   = (const float*)d_in[0];
    const float* edges   = (const float*)d_in[1];
    const float* glob    = (const float*)d_in[2];
    const int*   senders = (const int*)d_in[3];
    const int*   recvrs  = (const int*)d_in[4];
    const float* ne_W0 = (const float*)d_in[5],  *ne_b0 = (const float*)d_in[6];
    const float* ne_W1 = (const float*)d_in[7],  *ne_b1 = (const float*)d_in[8];
    const float* ee_W0 = (const float*)d_in[9],  *ee_b0 = (const float*)d_in[10];
    const float* ee_W1 = (const float*)d_in[11], *ee_b1 = (const float*)d_in[12];
    const float* eu_W0 = (const float*)d_in[13], *eu_b0 = (const float*)d_in[14];
    const float* eu_W1 = (const float*)d_in[15], *eu_b1 = (const float*)d_in[16];
    const float* nu_W0 = (const float*)d_in[17], *nu_b0 = (const float*)d_in[18];
    const float* nu_W1 = (const float*)d_in[19], *nu_b1 = (const float*)d_in[20];
    const float* ln_s  = (const float*)d_in[21], *ln_b  = (const float*)d_in[22];
    const float* dc_W0 = (const float*)d_in[23], *dc_b0 = (const float*)d_in[24];
    const float* dc_W1 = (const float*)d_in[25], *dc_b1 = (const float*)d_in[26];

    const int N = 50000, E = 500000;

    const int KD[13] = {32, 128, 32, 128, 384, 384, 128, 128, 256, 256, 128, 128, 128};
    const int KC[13] = {7, 128, 3, 128, 384, 384, 128, 128, 256, 256, 128, 128, 128};
    int pre[14]; pre[0] = 0;
    for (int i = 0; i < 13; ++i) pre[i + 1] = pre[i] + KD[i] * 128;
    const int totalPack = pre[13];

    char* ws = (char*)d_ws;
    size_t off = 0;
    auto alloc = [&](size_t bytes) -> char* {
        char* p = ws + off;
        off = (off + bytes + 255) & ~(size_t)255;
        return p;
    };
    bf16*  Wp      = (bf16*)alloc((size_t)totalPack * 2);
    float* b0e_eu  = (float*)alloc(2 * 128 * 4);
    float* b0e_nu  = (float*)alloc(2 * 128 * 4);
    bf16*  nh_b    = (bf16*)alloc((size_t)N * 128 * 2);      // 12.8 MB
    bf16*  recvb   = (bf16*)alloc((size_t)N * 128 * 2);      // 12.8 MB
    bf16*  newe    = (bf16*)alloc((size_t)E * 128 * 2);      // 128 MB
    int*   deg     = (int*)alloc((size_t)N * 4);
    int*   cursor  = (int*)alloc((size_t)N * 4);
    int*   bsum    = (int*)alloc(256 * 4);
    float* edges_s = (float*)alloc((size_t)E * 3 * 4);       // 6 MB sorted raw feats
    int*   sendp   = (int*)alloc((size_t)E * 4);
    int*   recvp   = (int*)alloc((size_t)E * 4);
    // total ~164 MB (proven-good envelope)

    if (off > ws_size) return;  // clean diagnostic instead of OOB fault

    PackArgs pa;
    const float* srcs[13] = {
        ne_W0, ne_W1, ee_W0, ee_W1,
        eu_W0, eu_W0 + (size_t)386 * 128,
        eu_W1, eu_W1 + (size_t)128 * 128,
        nu_W0, nu_W0 + (size_t)258 * 128,
        nu_W1, nu_W1 + (size_t)128 * 128,
        dc_W0};
    for (int i = 0; i < 13; ++i) { pa.d[i].src = srcs[i]; pa.d[i].Kcopy = KC[i]; pa.d[i].dstOff = pre[i]; }

    pack_all_kernel<<<(totalPack + 255) / 256, 256, 0, stream>>>(pa, Wp, totalPack);
    fold_bias_kernel<<<1, 128, 0, stream>>>(glob, eu_W0, eu_b0, nu_W0, nu_b0, b0e_eu, b0e_nu);

    // ---- receiver counting-sort ----
    const int gEdge = (E + 255) / 256;
    const int nb = (N + 255) / 256;
    zero_kernel<<<(N / 4 + 255) / 256, 256, 0, stream>>>((float4*)deg, N / 4);
    hist_kernel<<<gEdge, 256, 0, stream>>>(recvrs, deg, E);
    scan_part_kernel<<<nb, 256, 0, stream>>>(deg, cursor, bsum, N);
    scan_top_kernel<<<1, 256, 0, stream>>>(bsum, nb);
    scan_add_kernel<<<nb, 256, 0, stream>>>(cursor, bsum, N);
    scatter_kernel<<<gEdge, 256, 0, stream>>>(senders, recvrs, edges, cursor,
                                              edges_s, sendp, recvp, E);
    // cursor now holds CSR end-offsets

    const int gN = (N + 63) / 64, gE = (E + 63) / 64;
    mlp2_kernel<0, 32, 7><<<gN, 256, 0, stream>>>(
        nodes, nullptr, Wp + pre[0], ne_b0, Wp + pre[1], ne_b1,
        nullptr, nullptr, nh_b, N);

    for (int s = 0; s < 2; ++s) {
        if (s == 0)
            edge_kernel<0><<<gE, 256, 0, stream>>>(
                edges_s, sendp, recvp, nh_b, newe,
                Wp + pre[2], ee_b0, Wp + pre[3], ee_b1, ln_s, ln_b,
                Wp + pre[4], b0e_eu, Wp + pre[6], eu_b1, E);
        else
            edge_kernel<1><<<gE, 256, 0, stream>>>(
                edges_s, sendp, recvp, nh_b, newe,
                Wp + pre[2], ee_b0, Wp + pre[3], ee_b1, ln_s, ln_b,
                Wp + pre[5], b0e_eu + 128, Wp + pre[7], eu_b1 + 128, E);
        segsum_kernel<<<(N + 3) / 4, 256, 0, stream>>>(newe, cursor, recvb, N);
        mlp2_kernel<3, 256, 0><<<gN, 256, 0, stream>>>(
            nh_b, recvb, Wp + pre[8 + s], b0e_nu + s * 128,
            Wp + pre[10 + s], nu_b1 + s * 128, ln_s, ln_b, nh_b, N);
    }

    mlp2_kernel<4, 128, 0><<<gN, 256, 0, stream>>>(
        nh_b, nullptr, Wp + pre[12], dc_b0, nullptr, nullptr,
        dc_W1, dc_b1, d_out, N);
}

// Round 13
// 821.936 us; speedup vs baseline: 1.5528x; 1.0068x over previous
//
#include <hip/hip_runtime.h>
#include <hip/hip_bf16.h>

// GraphConvNet on MI355X — round 13: CONVOY-BREAKING chunk rotation.
// Smoking gun (r9): cutting 3300 VALU cyc/wave cut wall by exactly 3300 cyc/wave
// -> resident waves give ZERO mutual latency hiding: all waves on a CU run the
// same straight-line code, reach the same B-chunk load together, miss L1
// together (same 8KB!), and serialize on ~21 full L2 round trips (~18k cyc).
// Fix: per-wave rotated chunk order ro=(w+blockIdx)&3 within each GEMM's chunk
// group. First toucher warms L1; rotated followers hit L1; stalls interleave.
// Accumulation over chunks is commutative (fp32 reorder only). eh fragments now
// read from wave-private Hw LDS (LN'd eh1 written back, 4x ds_write_b128) to
// allow runtime chunk indices; frees 16 VGPRs. Node kernels unchanged (r10).
//
// MFMA fragment facts (guide §3, m89/m91/m120 verified):
//   A: lane holds A[m=lane&15][k=(lane>>4)*8+j]
//   B: lane holds B[k=(lane>>4)*8+j][n=lane&15]
//   C/D: lane reg r holds C[row=(lane>>4)*4+r][col=lane&15]

typedef __bf16 bf16;
typedef __attribute__((ext_vector_type(8))) __bf16 bf16x8;
typedef __attribute__((ext_vector_type(2))) __bf16 bf16x2;
typedef __attribute__((ext_vector_type(4))) float f32x4;

__device__ __forceinline__ float gelu_t(float x) {
    // exact identity: 0.5x(1+tanh(u)) == x*sigmoid(2u) = x/(1+exp(-2u))
    const float kn0 = -1.5957691216057308f;   // -2*sqrt(2/pi)
    const float kn1 = -0.07135481627159855f;  // -2*sqrt(2/pi)*0.044715
    float x2 = x * x;
    float w = x * __builtin_fmaf(kn1, x2, kn0);
    float e = __expf(w);
    return __fdividef(x, 1.0f + e);
}

// ---------------- weight packing: [K,128] fp32 -> bf16 [K/8][128][8] ----------------
struct PackDesc { const float* src; int Kcopy; int dstOff; };
struct PackArgs { PackDesc d[13]; };

__global__ __launch_bounds__(256) void pack_all_kernel(PackArgs pa, bf16* dst, int total) {
    int i = blockIdx.x * 256 + threadIdx.x;
    if (i >= total) return;
    int s = 0;
#pragma unroll
    for (int j = 1; j < 13; ++j) if (i >= pa.d[j].dstOff) s = j;
    int local = i - pa.d[s].dstOff;
    int k = local >> 7, n = local & 127;
    float v = (k < pa.d[s].Kcopy) ? pa.d[s].src[(size_t)k * 128 + n] : 0.0f;
    dst[pa.d[s].dstOff + ((k >> 3) * 128 + n) * 8 + (k & 7)] = (bf16)v;
}

__global__ void fold_bias_kernel(const float* g, const float* euW0, const float* eub0,
                                 const float* nuW0, const float* nub0,
                                 float* eu_eff, float* nu_eff) {
    int t = threadIdx.x;
    if (t < 128) {
        float g0 = g[0], g1 = g[1];
#pragma unroll
        for (int s = 0; s < 2; ++s) {
            eu_eff[s * 128 + t] = eub0[s * 128 + t]
                + g0 * euW0[((size_t)s * 386 + 384) * 128 + t]
                + g1 * euW0[((size_t)s * 386 + 385) * 128 + t];
            nu_eff[s * 128 + t] = nub0[s * 128 + t]
                + g0 * nuW0[((size_t)s * 258 + 256) * 128 + t]
                + g1 * nuW0[((size_t)s * 258 + 257) * 128 + t];
        }
    }
}

__global__ __launch_bounds__(256) void zero_kernel(float4* p, int n4) {
    int i = blockIdx.x * 256 + threadIdx.x;
    if (i < n4) p[i] = float4{0.0f, 0.0f, 0.0f, 0.0f};
}

// ---------------- receiver-sort (counting sort) ----------------
__global__ __launch_bounds__(256) void hist_kernel(const int* __restrict__ recv,
                                                   int* __restrict__ deg, int E) {
    int e = blockIdx.x * 256 + threadIdx.x;
    if (e < E) atomicAdd(&deg[recv[e]], 1);
}

__global__ __launch_bounds__(256) void scan_part_kernel(const int* __restrict__ deg,
                                                        int* __restrict__ cursor,
                                                        int* __restrict__ bsum, int n) {
    __shared__ int tmp[256];
    int t = threadIdx.x, g = blockIdx.x * 256 + t;
    int v = (g < n) ? deg[g] : 0;
    tmp[t] = v; __syncthreads();
#pragma unroll
    for (int o = 1; o < 256; o <<= 1) {
        int x = (t >= o) ? tmp[t - o] : 0;
        __syncthreads();
        tmp[t] += x;
        __syncthreads();
    }
    if (g < n) cursor[g] = tmp[t] - v;
    if (t == 255) bsum[blockIdx.x] = tmp[255];
}

__global__ void scan_top_kernel(int* bsum, int nb) {  // single block, nb<=256
    __shared__ int tmp[256];
    int t = threadIdx.x;
    int v = (t < nb) ? bsum[t] : 0;
    tmp[t] = v; __syncthreads();
#pragma unroll
    for (int o = 1; o < 256; o <<= 1) {
        int x = (t >= o) ? tmp[t - o] : 0;
        __syncthreads();
        tmp[t] += x;
        __syncthreads();
    }
    if (t < nb) bsum[t] = tmp[t] - v;
}

__global__ __launch_bounds__(256) void scan_add_kernel(int* __restrict__ cursor,
                                                       const int* __restrict__ bsum, int n) {
    int g = blockIdx.x * 256 + threadIdx.x;
    if (g < n) cursor[g] += bsum[blockIdx.x];
}

// scatter: also pre-sorts raw edge features (edges_s[pos] = edges[e])
__global__ __launch_bounds__(256) void scatter_kernel(
    const int* __restrict__ send, const int* __restrict__ recv,
    const float* __restrict__ edges_raw, int* __restrict__ cursor,
    float* __restrict__ edges_s, int* __restrict__ sendp, int* __restrict__ recvp, int E) {
    int e = blockIdx.x * 256 + threadIdx.x;
    if (e >= E) return;
    int r = recv[e];
    int pos = atomicAdd(&cursor[r], 1);
    sendp[pos] = send[e]; recvp[pos] = r;
    edges_s[(size_t)pos * 3]     = edges_raw[(size_t)e * 3];
    edges_s[(size_t)pos * 3 + 1] = edges_raw[(size_t)e * 3 + 1];
    edges_s[(size_t)pos * 3 + 2] = edges_raw[(size_t)e * 3 + 2];
}
// after scatter: cursor[i] == end offset of node i's segment (CSR row end)

// ---------------- segment-sum: recvb[i] = sum of newe rows in [start,end) ----------------
__global__ __launch_bounds__(256) void segsum_kernel(const bf16* __restrict__ newe,
                                                     const int* __restrict__ endoff,
                                                     bf16* __restrict__ recvb, int N) {
    int node = blockIdx.x * 4 + (threadIdx.x >> 6);
    if (node >= N) return;
    int lane = threadIdx.x & 63;
    int start = (node == 0) ? 0 : endoff[node - 1];
    int end = endoff[node];
    float s0 = 0.0f, s1 = 0.0f, t0 = 0.0f, t1 = 0.0f;
    int e = start;
    for (; e + 1 < end; e += 2) {
        bf16x2 v = *(const bf16x2*)(newe + (size_t)e * 128 + lane * 2);
        bf16x2 u = *(const bf16x2*)(newe + (size_t)(e + 1) * 128 + lane * 2);
        s0 += (float)v[0]; s1 += (float)v[1];
        t0 += (float)u[0]; t1 += (float)u[1];
    }
    if (e < end) {
        bf16x2 v = *(const bf16x2*)(newe + (size_t)e * 128 + lane * 2);
        s0 += (float)v[0]; s1 += (float)v[1];
    }
    bf16x2 o; o[0] = (bf16)(s0 + t0); o[1] = (bf16)(s1 + t1);
    *(bf16x2*)(recvb + (size_t)node * 128 + lane * 2) = o;
}

// ---------------- edge megakernel: embed(recompute) [+LN skip] + step MLP ----------------
// STEP 0: new_e1 = MLP_s0(concat(eh0, nh_s, nh_r)+g)        ; newe <- new_e1
// STEP 1: eh1 = LN(eh0+newe1); new_e2 = MLP_s1(concat(...)) ; newe <- new_e2 (in-place)
// Per-wave rotated chunk order (ro) breaks the inter-wave convoy on B-chunks.
template <int STEP>
__global__ __launch_bounds__(256, 3) void edge_kernel(
    const float* __restrict__ edges_s,
    const int* __restrict__ sendp, const int* __restrict__ recvp,
    const bf16* __restrict__ nh_b, bf16* __restrict__ newe,
    const bf16* __restrict__ We0, const float* __restrict__ be0,
    const bf16* __restrict__ We1, const float* __restrict__ be1,
    const float* __restrict__ ln_s, const float* __restrict__ ln_b,
    const bf16* __restrict__ Ws0, const float* __restrict__ bs0,
    const bf16* __restrict__ Ws1, const float* __restrict__ bs1,
    int E)
{
    __shared__ __align__(16) bf16 Hsep[4 * 16 * 136];
    const int tid = threadIdx.x, lane = tid & 63, w = tid >> 6;
    const int n16 = lane & 15, quad = lane >> 4;
    const int m0 = blockIdx.x * 64;
    int m = m0 + w * 16 + n16; if (m >= E) m = E - 1;
    const int sIdx = sendp[m], rIdx = recvp[m];
    const int ro = (w + blockIdx.x) & 3;   // convoy-breaking rotation

    bf16* Hw = &Hsep[w * 16 * 136];
    const f32x4 z = {0.0f, 0.0f, 0.0f, 0.0f};
    f32x4 acc[8];
    bf16x8 bq[8], bq2[8];

    // ---- embed GEMM1 (K=32; single chunk; quad0 carries the 3 raw feats) ----
#pragma unroll
    for (int t = 0; t < 8; ++t) acc[t] = z;
    {
        bf16x8 a;
#pragma unroll
        for (int j = 0; j < 8; ++j) a[j] = (bf16)0.0f;
        if (quad == 0) {
            a[0] = (bf16)edges_s[(size_t)m * 3];
            a[1] = (bf16)edges_s[(size_t)m * 3 + 1];
            a[2] = (bf16)edges_s[(size_t)m * 3 + 2];
        }
        const bf16* bp = We0 + ((size_t)(quad * 128 + n16)) * 8;
#pragma unroll
        for (int t = 0; t < 8; ++t) {
            bf16x8 b = *(const bf16x8*)(bp + t * 128);
            acc[t] = __builtin_amdgcn_mfma_f32_16x16x32_bf16(a, b, acc[t], 0, 0, 0);
        }
    }
    // gelu + be0 -> Hw (A-layout)
#pragma unroll
    for (int t = 0; t < 8; ++t) {
        float bb = be0[t * 16 + n16];
#pragma unroll
        for (int r = 0; r < 4; ++r)
            Hw[(quad * 4 + r) * 136 + t * 16 + n16] = (bf16)gelu_t(acc[t][r] + bb);
    }

    // ---- embed GEMM2 (K=128, 4 chunks rotated, B double-buffered) ----
#pragma unroll
    for (int t = 0; t < 8; ++t) acc[t] = z;
    {
        const bf16* bp0 = We1 + ((size_t)((ro * 4 + quad) * 128 + n16)) * 8;
#pragma unroll
        for (int t = 0; t < 8; ++t) bq[t] = *(const bf16x8*)(bp0 + t * 128);
    }
#pragma unroll
    for (int c = 0; c < 4; ++c) {
        int cc = (c + ro) & 3;
        if (c + 1 < 4) {
            int cn = (c + 1 + ro) & 3;
            const bf16* bp2 = We1 + ((size_t)((cn * 4 + quad) * 128 + n16)) * 8;
#pragma unroll
            for (int t = 0; t < 8; ++t) bq2[t] = *(const bf16x8*)(bp2 + t * 128);
        }
        bf16x8 a = *(const bf16x8*)&Hw[n16 * 136 + cc * 32 + quad * 8];
#pragma unroll
        for (int t = 0; t < 8; ++t)
            acc[t] = __builtin_amdgcn_mfma_f32_16x16x32_bf16(a, bq[t], acc[t], 0, 0, 0);
#pragma unroll
        for (int t = 0; t < 8; ++t) bq[t] = bq2[t];
    }
    // eh0 (+be1) -> Hw (A-layout via C-layout writes, as before)
#pragma unroll
    for (int t = 0; t < 8; ++t) {
        float bb = be1[t * 16 + n16];
#pragma unroll
        for (int r = 0; r < 4; ++r)
            Hw[(quad * 4 + r) * 136 + t * 16 + n16] = (bf16)(acc[t][r] + bb);
    }

    if constexpr (STEP == 1) {
        // eh1 = LN(eh0 + newe1); read A-frags from Hw, write LN'd back (b128)
        float x[4][8];
        float sm = 0.0f, sq = 0.0f;
#pragma unroll
        for (int c = 0; c < 4; ++c) {
            bf16x8 ev = *(const bf16x8*)&Hw[n16 * 136 + c * 32 + quad * 8];
            bf16x8 ne = *(const bf16x8*)(newe + (size_t)m * 128 + c * 32 + quad * 8);
#pragma unroll
            for (int j = 0; j < 8; ++j) {
                float v = (float)ev[j] + (float)ne[j];
                x[c][j] = v; sm += v; sq += v * v;
            }
        }
        sm += __shfl_xor(sm, 16); sq += __shfl_xor(sq, 16);
        sm += __shfl_xor(sm, 32); sq += __shfl_xor(sq, 32);
        float mean = sm * (1.0f / 128.0f);
        float inv = rsqrtf(sq * (1.0f / 128.0f) - mean * mean + 1e-6f);
#pragma unroll
        for (int c = 0; c < 4; ++c) {
            bf16x8 o;
#pragma unroll
            for (int j = 0; j < 8; ++j) {
                int col = c * 32 + quad * 8 + j;
                o[j] = (bf16)((x[c][j] - mean) * inv * ln_s[col] + ln_b[col]);
            }
            *(bf16x8*)&Hw[n16 * 136 + c * 32 + quad * 8] = o;
        }
    }

    // ---- step GEMM1: K=384, 3 groups x 4 rotated chunks; B double-buffered ----
#pragma unroll
    for (int t = 0; t < 8; ++t) acc[t] = z;
    {
        const bf16* bp0 = Ws0 + ((size_t)((ro * 4 + quad) * 128 + n16)) * 8;
#pragma unroll
        for (int t = 0; t < 8; ++t) bq[t] = *(const bf16x8*)(bp0 + t * 128);
    }
    // Group A: chunks (c+ro)&3, A from LDS (eh)
#pragma unroll
    for (int c = 0; c < 4; ++c) {
        int cc = (c + ro) & 3;
        int cn = (c < 3) ? ((c + 1 + ro) & 3) : (4 + ro);
        const bf16* bp2 = Ws0 + ((size_t)((cn * 4 + quad) * 128 + n16)) * 8;
#pragma unroll
        for (int t = 0; t < 8; ++t) bq2[t] = *(const bf16x8*)(bp2 + t * 128);
        bf16x8 a = *(const bf16x8*)&Hw[n16 * 136 + cc * 32 + quad * 8];
#pragma unroll
        for (int t = 0; t < 8; ++t)
            acc[t] = __builtin_amdgcn_mfma_f32_16x16x32_bf16(a, bq[t], acc[t], 0, 0, 0);
#pragma unroll
        for (int t = 0; t < 8; ++t) bq[t] = bq2[t];
    }
    // Group B: chunks 4+((c+ro)&3), A from nh_b[sIdx]
#pragma unroll
    for (int c = 0; c < 4; ++c) {
        int cc = 4 + ((c + ro) & 3);
        int cn = (c < 3) ? (4 + ((c + 1 + ro) & 3)) : (8 + ro);
        const bf16* bp2 = Ws0 + ((size_t)((cn * 4 + quad) * 128 + n16)) * 8;
#pragma unroll
        for (int t = 0; t < 8; ++t) bq2[t] = *(const bf16x8*)(bp2 + t * 128);
        bf16x8 a = *(const bf16x8*)(nh_b + (size_t)sIdx * 128 + (cc & 3) * 32 + quad * 8);
#pragma unroll
        for (int t = 0; t < 8; ++t)
            acc[t] = __builtin_amdgcn_mfma_f32_16x16x32_bf16(a, bq[t], acc[t], 0, 0, 0);
#pragma unroll
        for (int t = 0; t < 8; ++t) bq[t] = bq2[t];
    }
    // Group C: chunks 8+((c+ro)&3), A from nh_b[rIdx]
#pragma unroll
    for (int c = 0; c < 4; ++c) {
        int cc = 8 + ((c + ro) & 3);
        if (c < 3) {
            int cn = 8 + ((c + 1 + ro) & 3);
            const bf16* bp2 = Ws0 + ((size_t)((cn * 4 + quad) * 128 + n16)) * 8;
#pragma unroll
            for (int t = 0; t < 8; ++t) bq2[t] = *(const bf16x8*)(bp2 + t * 128);
        }
        bf16x8 a = *(const bf16x8*)(nh_b + (size_t)rIdx * 128 + (cc & 3) * 32 + quad * 8);
#pragma unroll
        for (int t = 0; t < 8; ++t)
            acc[t] = __builtin_amdgcn_mfma_f32_16x16x32_bf16(a, bq[t], acc[t], 0, 0, 0);
        if (c < 3) {
#pragma unroll
            for (int t = 0; t < 8; ++t) bq[t] = bq2[t];
        }
    }
    // gelu + bs0 -> Hw
#pragma unroll
    for (int t = 0; t < 8; ++t) {
        float bb = bs0[t * 16 + n16];
#pragma unroll
        for (int r = 0; r < 4; ++r)
            Hw[(quad * 4 + r) * 136 + t * 16 + n16] = (bf16)gelu_t(acc[t][r] + bb);
    }
    // ---- step GEMM2 (K=128, 4 chunks rotated, B double-buffered) -> new_e ----
#pragma unroll
    for (int t = 0; t < 8; ++t) acc[t] = z;
    {
        const bf16* bp0 = Ws1 + ((size_t)((ro * 4 + quad) * 128 + n16)) * 8;
#pragma unroll
        for (int t = 0; t < 8; ++t) bq[t] = *(const bf16x8*)(bp0 + t * 128);
    }
#pragma unroll
    for (int c = 0; c < 4; ++c) {
        int cc = (c + ro) & 3;
        if (c + 1 < 4) {
            int cn = (c + 1 + ro) & 3;
            const bf16* bp2 = Ws1 + ((size_t)((cn * 4 + quad) * 128 + n16)) * 8;
#pragma unroll
            for (int t = 0; t < 8; ++t) bq2[t] = *(const bf16x8*)(bp2 + t * 128);
        }
        bf16x8 a = *(const bf16x8*)&Hw[n16 * 136 + cc * 32 + quad * 8];
#pragma unroll
        for (int t = 0; t < 8; ++t)
            acc[t] = __builtin_amdgcn_mfma_f32_16x16x32_bf16(a, bq[t], acc[t], 0, 0, 0);
#pragma unroll
        for (int t = 0; t < 8; ++t) bq[t] = bq2[t];
    }
    // store new_e (guarded)
#pragma unroll
    for (int t = 0; t < 8; ++t) {
        float bb = bs1[t * 16 + n16];
#pragma unroll
        for (int r = 0; r < 4; ++r) {
            int row = m0 + w * 16 + quad * 4 + r;
            if (row < E)
                newe[(size_t)row * 128 + t * 16 + n16] = (bf16)(acc[t][r] + bb);
        }
    }
}

// ---------------- node kernels (r10 structure, unchanged) ----------------
// MODE 0: embed nodes  (K1=32, raw 7)  fp32 in  -> bf16 nh_b
// MODE 3: node update  (K1=256) bf16 nh_b + bf16 recvb -> bf16 nh_b in-place, skip+LN
// MODE 4: fused decode: bf16 nh_b -> GEMM1+gelu -> dot dec_W1[128,3] -> fp32 out[N,3]
template <int MODE, int K1, int RAWF>
__global__ __launch_bounds__(256, 5) void mlp2_kernel(
    const void* __restrict__ Araw0v, const bf16* __restrict__ Araw1b,
    const bf16* __restrict__ W0p, const float* __restrict__ b0,
    const bf16* __restrict__ W1p, const float* __restrict__ b1,
    const float* __restrict__ ln_s, const float* __restrict__ ln_b,
    void* out0v, int Mtotal)
{
    __shared__ __align__(16) bf16 Hsep[(MODE == 4) ? 1 : (4 * 16 * 136)];

    const int tid = threadIdx.x, lane = tid & 63, w = tid >> 6;
    const int n16 = lane & 15, quad = lane >> 4;
    const int m0 = blockIdx.x * 64;

    const float* Araw0f = (const float*)Araw0v;
    const bf16*  Araw0b = (const bf16*)Araw0v;
    float* out0f = (float*)out0v;
    bf16*  out0b = (bf16*)out0v;

    int m = m0 + w * 16 + n16;
    if (m >= Mtotal) m = Mtotal - 1;

    const f32x4 z = {0.0f, 0.0f, 0.0f, 0.0f};
    f32x4 acc[8];
#pragma unroll
    for (int t = 0; t < 8; ++t) acc[t] = z;

    // ---- GEMM1 ----
#pragma unroll
    for (int c = 0; c < K1 / 32; ++c) {
        const int k0 = c * 32 + quad * 8;
        bf16x8 a;
        if constexpr (MODE == 3) {
            if (c < 4) a = *(const bf16x8*)(Araw0b + (size_t)m * 128 + k0);
            else       a = *(const bf16x8*)(Araw1b + (size_t)m * 128 + (k0 - 128));
        } else if constexpr (MODE == 4) {
            a = *(const bf16x8*)(Araw0b + (size_t)m * 128 + k0);
        } else {  // MODE 0: RAWF raw features (<8), only quad 0 nonzero
#pragma unroll
            for (int j = 0; j < 8; ++j) a[j] = (bf16)0.0f;
            if (quad == 0) {
#pragma unroll
                for (int j = 0; j < RAWF; ++j)
                    a[j] = (bf16)Araw0f[(size_t)m * RAWF + j];
            }
        }
        const bf16* bp = W0p + ((size_t)((c * 4 + quad) * 128 + n16)) * 8;
#pragma unroll
        for (int t = 0; t < 8; ++t) {
            bf16x8 b = *(const bf16x8*)(bp + t * 128);
            acc[t] = __builtin_amdgcn_mfma_f32_16x16x32_bf16(a, b, acc[t], 0, 0, 0);
        }
    }

    float b0v[8];
#pragma unroll
    for (int t = 0; t < 8; ++t) b0v[t] = b0[t * 16 + n16];

    if constexpr (MODE == 4) {
        // fused decode: h = gelu(acc+b0); out[row,o] = sum_col h*W1[col,o] + b1[o]
        const float* W1d = ln_s;
        const float* b1d = ln_b;
        float p[4][3];
#pragma unroll
        for (int r = 0; r < 4; ++r) { p[r][0] = 0; p[r][1] = 0; p[r][2] = 0; }
#pragma unroll
        for (int t = 0; t < 8; ++t) {
            int col = t * 16 + n16;
            float w0 = W1d[col * 3 + 0], w1 = W1d[col * 3 + 1], w2 = W1d[col * 3 + 2];
#pragma unroll
            for (int r = 0; r < 4; ++r) {
                float h = gelu_t(acc[t][r] + b0v[t]);
                p[r][0] += h * w0; p[r][1] += h * w1; p[r][2] += h * w2;
            }
        }
#pragma unroll
        for (int mm = 1; mm < 16; mm <<= 1)
#pragma unroll
            for (int r = 0; r < 4; ++r) {
                p[r][0] += __shfl_xor(p[r][0], mm);
                p[r][1] += __shfl_xor(p[r][1], mm);
                p[r][2] += __shfl_xor(p[r][2], mm);
            }
        if (n16 < 3) {
            float bb = b1d[n16];
#pragma unroll
            for (int r = 0; r < 4; ++r) {
                int row = m0 + w * 16 + quad * 4 + r;
                if (row < Mtotal)
                    out0f[(size_t)row * 3 + n16] = p[r][n16] + bb;
            }
        }
        return;
    }

    // hidden -> A-layout via wave-private LDS slab
    bf16* Hw = &Hsep[w * 16 * 136];
#pragma unroll
    for (int t = 0; t < 8; ++t)
#pragma unroll
        for (int r = 0; r < 4; ++r)
            Hw[(quad * 4 + r) * 136 + t * 16 + n16] = (bf16)gelu_t(acc[t][r] + b0v[t]);

    // ---- GEMM2 (K=128) ----
#pragma unroll
    for (int t = 0; t < 8; ++t) acc[t] = z;
#pragma unroll
    for (int kc = 0; kc < 128; kc += 32) {
        bf16x8 a = *(const bf16x8*)&Hw[n16 * 136 + kc + quad * 8];
        const bf16* bp = W1p + ((size_t)(((kc >> 3) + quad) * 128 + n16)) * 8;
#pragma unroll
        for (int t = 0; t < 8; ++t) {
            bf16x8 b = *(const bf16x8*)(bp + t * 128);
            acc[t] = __builtin_amdgcn_mfma_f32_16x16x32_bf16(a, b, acc[t], 0, 0, 0);
        }
    }

    if constexpr (MODE == 0) {  // embed nodes: plain bf16 store
#pragma unroll
        for (int t = 0; t < 8; ++t) {
            float b1v = b1[t * 16 + n16];
#pragma unroll
            for (int r = 0; r < 4; ++r) {
                int row = m0 + w * 16 + quad * 4 + r;
                if (row < Mtotal)
                    out0b[(size_t)row * 128 + t * 16 + n16] = (bf16)(acc[t][r] + b1v);
            }
        }
        return;
    }

    // ---- MODE 3 epilogue: skip + LayerNorm ----
    float b1v[8], scl[8], bia[8];
#pragma unroll
    for (int t = 0; t < 8; ++t) {
        int col = t * 16 + n16;
        b1v[t] = b1[col]; scl[t] = ln_s[col]; bia[t] = ln_b[col];
    }
    int rowg[4];
#pragma unroll
    for (int r = 0; r < 4; ++r) rowg[r] = m0 + w * 16 + quad * 4 + r;
    float x[8][4];
    float sm[4] = {0, 0, 0, 0}, sq[4] = {0, 0, 0, 0};
#pragma unroll
    for (int t = 0; t < 8; ++t) {
        int col = t * 16 + n16;
#pragma unroll
        for (int r = 0; r < 4; ++r) {
            bool ok = rowg[r] < Mtotal;
            float v = acc[t][r] + b1v[t];
            float old = ok ? (float)Araw0b[(size_t)rowg[r] * 128 + col] : 0.0f;
            float xx = old + v;
            x[t][r] = xx; sm[r] += xx; sq[r] += xx * xx;
        }
    }
#pragma unroll
    for (int mm = 1; mm < 16; mm <<= 1)
#pragma unroll
        for (int r = 0; r < 4; ++r) {
            sm[r] += __shfl_xor(sm[r], mm);
            sq[r] += __shfl_xor(sq[r], mm);
        }
    float mean[4], inv[4];
#pragma unroll
    for (int r = 0; r < 4; ++r) {
        mean[r] = sm[r] * (1.0f / 128.0f);
        float var = sq[r] * (1.0f / 128.0f) - mean[r] * mean[r];
        inv[r] = rsqrtf(var + 1e-6f);
    }
#pragma unroll
    for (int t = 0; t < 8; ++t)
#pragma unroll
        for (int r = 0; r < 4; ++r)
            if (rowg[r] < Mtotal)
                out0b[(size_t)rowg[r] * 128 + t * 16 + n16] =
                    (bf16)((x[t][r] - mean[r]) * inv[r] * scl[t] + bia[t]);
}

extern "C" void kernel_launch(void* const* d_in, const int* in_sizes, int n_in,
                              void* d_out, int out_size, void* d_ws, size_t ws_size,
                              hipStream_t stream) {
    const float* nodes   = (const float*)d_in[0];
    const float* edges   = (const float*)d_in[1];
    const float* glob    = (const float*)d_in[2];
    const int*   senders = (const int*)d_in[3];
    const int*   recvrs  = (const int*)d_in[4];
    const float* ne_W0 = (const float*)d_in[5],  *ne_b0 = (const float*)d_in[6];
    const float* ne_W1 = (const float*)d_in[7],  *ne_b1 = (const float*)d_in[8];
    const float* ee_W0 = (const float*)d_in[9],  *ee_b0 = (const float*)d_in[10];
    const float* ee_W1 = (const float*)d_in[11], *ee_b1 = (const float*)d_in[12];
    const float* eu_W0 = (const float*)d_in[13], *eu_b0 = (const float*)d_in[14];
    const float* eu_W1 = (const float*)d_in[15], *eu_b1 = (const float*)d_in[16];
    const float* nu_W0 = (const float*)d_in[17], *nu_b0 = (const float*)d_in[18];
    const float* nu_W1 = (const float*)d_in[19], *nu_b1 = (const float*)d_in[20];
    const float* ln_s  = (const float*)d_in[21], *ln_b  = (const float*)d_in[22];
    const float* dc_W0 = (const float*)d_in[23], *dc_b0 = (const float*)d_in[24];
    const float* dc_W1 = (const float*)d_in[25], *dc_b1 = (const float*)d_in[26];

    const int N = 50000, E = 500000;

    const int KD[13] = {32, 128, 32, 128, 384, 384, 128, 128, 256, 256, 128, 128, 128};
    const int KC[13] = {7, 128, 3, 128, 384, 384, 128, 128, 256, 256, 128, 128, 128};
    int pre[14]; pre[0] = 0;
    for (int i = 0; i < 13; ++i) pre[i + 1] = pre[i] + KD[i] * 128;
    const int totalPack = pre[13];

    char* ws = (char*)d_ws;
    size_t off = 0;
    auto alloc = [&](size_t bytes) -> char* {
        char* p = ws + off;
        off = (off + bytes + 255) & ~(size_t)255;
        return p;
    };
    bf16*  Wp      = (bf16*)alloc((size_t)totalPack * 2);
    float* b0e_eu  = (float*)alloc(2 * 128 * 4);
    float* b0e_nu  = (float*)alloc(2 * 128 * 4);
    bf16*  nh_b    = (bf16*)alloc((size_t)N * 128 * 2);      // 12.8 MB
    bf16*  recvb   = (bf16*)alloc((size_t)N * 128 * 2);      // 12.8 MB
    bf16*  newe    = (bf16*)alloc((size_t)E * 128 * 2);      // 128 MB
    int*   deg     = (int*)alloc((size_t)N * 4);
    int*   cursor  = (int*)alloc((size_t)N * 4);
    int*   bsum    = (int*)alloc(256 * 4);
    float* edges_s = (float*)alloc((size_t)E * 3 * 4);       // 6 MB sorted raw feats
    int*   sendp   = (int*)alloc((size_t)E * 4);
    int*   recvp   = (int*)alloc((size_t)E * 4);
    // total ~164 MB (proven-good envelope)

    if (off > ws_size) return;  // clean diagnostic instead of OOB fault

    PackArgs pa;
    const float* srcs[13] = {
        ne_W0, ne_W1, ee_W0, ee_W1,
        eu_W0, eu_W0 + (size_t)386 * 128,
        eu_W1, eu_W1 + (size_t)128 * 128,
        nu_W0, nu_W0 + (size_t)258 * 128,
        nu_W1, nu_W1 + (size_t)128 * 128,
        dc_W0};
    for (int i = 0; i < 13; ++i) { pa.d[i].src = srcs[i]; pa.d[i].Kcopy = KC[i]; pa.d[i].dstOff = pre[i]; }

    pack_all_kernel<<<(totalPack + 255) / 256, 256, 0, stream>>>(pa, Wp, totalPack);
    fold_bias_kernel<<<1, 128, 0, stream>>>(glob, eu_W0, eu_b0, nu_W0, nu_b0, b0e_eu, b0e_nu);

    // ---- receiver counting-sort ----
    const int gEdge = (E + 255) / 256;
    const int nb = (N + 255) / 256;
    zero_kernel<<<(N / 4 + 255) / 256, 256, 0, stream>>>((float4*)deg, N / 4);
    hist_kernel<<<gEdge, 256, 0, stream>>>(recvrs, deg, E);
    scan_part_kernel<<<nb, 256, 0, stream>>>(deg, cursor, bsum, N);
    scan_top_kernel<<<1, 256, 0, stream>>>(bsum, nb);
    scan_add_kernel<<<nb, 256, 0, stream>>>(cursor, bsum, N);
    scatter_kernel<<<gEdge, 256, 0, stream>>>(senders, recvrs, edges, cursor,
                                              edges_s, sendp, recvp, E);
    // cursor now holds CSR end-offsets

    const int gN = (N + 63) / 64, gE = (E + 63) / 64;
    mlp2_kernel<0, 32, 7><<<gN, 256, 0, stream>>>(
        nodes, nullptr, Wp + pre[0], ne_b0, Wp + pre[1], ne_b1,
        nullptr, nullptr, nh_b, N);

    for (int s = 0; s < 2; ++s) {
        if (s == 0)
            edge_kernel<0><<<gE, 256, 0, stream>>>(
                edges_s, sendp, recvp, nh_b, newe,
                Wp + pre[2], ee_b0, Wp + pre[3], ee_b1, ln_s, ln_b,
                Wp + pre[4], b0e_eu, Wp + pre[6], eu_b1, E);
        else
            edge_kernel<1><<<gE, 256, 0, stream>>>(
                edges_s, sendp, recvp, nh_b, newe,
                Wp + pre[2], ee_b0, Wp + pre[3], ee_b1, ln_s, ln_b,
                Wp + pre[5], b0e_eu + 128, Wp + pre[7], eu_b1 + 128, E);
        segsum_kernel<<<(N + 3) / 4, 256, 0, stream>>>(newe, cursor, recvb, N);
        mlp2_kernel<3, 256, 0><<<gN, 256, 0, stream>>>(
            nh_b, recvb, Wp + pre[8 + s], b0e_nu + s * 128,
            Wp + pre[10 + s], nu_b1 + s * 128, ln_s, ln_b, nh_b, N);
    }

    mlp2_kernel<4, 128, 0><<<gN, 256, 0, stream>>>(
        nh_b, nullptr, Wp + pre[12], dc_b0, nullptr, nullptr,
        dc_W1, dc_b1, d_out, N);
}

// Round 14
// 760.739 us; speedup vs baseline: 1.6777x; 1.0804x over previous
//
#include <hip/hip_runtime.h>
#include <hip/hip_bf16.h>

// GraphConvNet on MI355X — round 14: revert edge to r10; harvest non-edge time.
// Edge kernel plateau (~287us) is robust: occupancy/prefetch/rotation/LDS-weights
// all falsified; only instruction-count cuts moved it (gelu 1:1). Non-edge is
// ~250us across 12 dispatches — attack that with proven patterns:
//   * segsum 4x-wide: 1 wave/node, 4 rows/iter, bf16x8 (16B) per lane,
//     shfl_xor(16/32) group combine. ~40 -> ~16us each.
//   * decode fused into last node update (MODE 5): LN out -> Hw (proven path)
//     -> GEMM1(dc_W0 packed) -> gelu -> [128,3] dot -> d_out. Kills MODE4
//     dispatch + 25.6MB nh round-trip.
//
// MFMA fragment facts (guide §3, m89/m91/m120 verified):
//   A: lane holds A[m=lane&15][k=(lane>>4)*8+j]
//   B: lane holds B[k=(lane>>4)*8+j][n=lane&15]
//   C/D: lane reg r holds C[row=(lane>>4)*4+r][col=lane&15]

typedef __bf16 bf16;
typedef __attribute__((ext_vector_type(8))) __bf16 bf16x8;
typedef __attribute__((ext_vector_type(2))) __bf16 bf16x2;
typedef __attribute__((ext_vector_type(4))) float f32x4;

__device__ __forceinline__ float gelu_t(float x) {
    // exact identity: 0.5x(1+tanh(u)) == x*sigmoid(2u) = x/(1+exp(-2u))
    const float kn0 = -1.5957691216057308f;   // -2*sqrt(2/pi)
    const float kn1 = -0.07135481627159855f;  // -2*sqrt(2/pi)*0.044715
    float x2 = x * x;
    float w = x * __builtin_fmaf(kn1, x2, kn0);
    float e = __expf(w);
    return __fdividef(x, 1.0f + e);
}

// ---------------- weight packing: [K,128] fp32 -> bf16 [K/8][128][8] ----------------
struct PackDesc { const float* src; int Kcopy; int dstOff; };
struct PackArgs { PackDesc d[13]; };

__global__ __launch_bounds__(256) void pack_all_kernel(PackArgs pa, bf16* dst, int total) {
    int i = blockIdx.x * 256 + threadIdx.x;
    if (i >= total) return;
    int s = 0;
#pragma unroll
    for (int j = 1; j < 13; ++j) if (i >= pa.d[j].dstOff) s = j;
    int local = i - pa.d[s].dstOff;
    int k = local >> 7, n = local & 127;
    float v = (k < pa.d[s].Kcopy) ? pa.d[s].src[(size_t)k * 128 + n] : 0.0f;
    dst[pa.d[s].dstOff + ((k >> 3) * 128 + n) * 8 + (k & 7)] = (bf16)v;
}

__global__ void fold_bias_kernel(const float* g, const float* euW0, const float* eub0,
                                 const float* nuW0, const float* nub0,
                                 float* eu_eff, float* nu_eff) {
    int t = threadIdx.x;
    if (t < 128) {
        float g0 = g[0], g1 = g[1];
#pragma unroll
        for (int s = 0; s < 2; ++s) {
            eu_eff[s * 128 + t] = eub0[s * 128 + t]
                + g0 * euW0[((size_t)s * 386 + 384) * 128 + t]
                + g1 * euW0[((size_t)s * 386 + 385) * 128 + t];
            nu_eff[s * 128 + t] = nub0[s * 128 + t]
                + g0 * nuW0[((size_t)s * 258 + 256) * 128 + t]
                + g1 * nuW0[((size_t)s * 258 + 257) * 128 + t];
        }
    }
}

__global__ __launch_bounds__(256) void zero_kernel(float4* p, int n4) {
    int i = blockIdx.x * 256 + threadIdx.x;
    if (i < n4) p[i] = float4{0.0f, 0.0f, 0.0f, 0.0f};
}

// ---------------- receiver-sort (counting sort) ----------------
__global__ __launch_bounds__(256) void hist_kernel(const int* __restrict__ recv,
                                                   int* __restrict__ deg, int E) {
    int e = blockIdx.x * 256 + threadIdx.x;
    if (e < E) atomicAdd(&deg[recv[e]], 1);
}

__global__ __launch_bounds__(256) void scan_part_kernel(const int* __restrict__ deg,
                                                        int* __restrict__ cursor,
                                                        int* __restrict__ bsum, int n) {
    __shared__ int tmp[256];
    int t = threadIdx.x, g = blockIdx.x * 256 + t;
    int v = (g < n) ? deg[g] : 0;
    tmp[t] = v; __syncthreads();
#pragma unroll
    for (int o = 1; o < 256; o <<= 1) {
        int x = (t >= o) ? tmp[t - o] : 0;
        __syncthreads();
        tmp[t] += x;
        __syncthreads();
    }
    if (g < n) cursor[g] = tmp[t] - v;
    if (t == 255) bsum[blockIdx.x] = tmp[255];
}

__global__ void scan_top_kernel(int* bsum, int nb) {  // single block, nb<=256
    __shared__ int tmp[256];
    int t = threadIdx.x;
    int v = (t < nb) ? bsum[t] : 0;
    tmp[t] = v; __syncthreads();
#pragma unroll
    for (int o = 1; o < 256; o <<= 1) {
        int x = (t >= o) ? tmp[t - o] : 0;
        __syncthreads();
        tmp[t] += x;
        __syncthreads();
    }
    if (t < nb) bsum[t] = tmp[t] - v;
}

__global__ __launch_bounds__(256) void scan_add_kernel(int* __restrict__ cursor,
                                                       const int* __restrict__ bsum, int n) {
    int g = blockIdx.x * 256 + threadIdx.x;
    if (g < n) cursor[g] += bsum[blockIdx.x];
}

// scatter: also pre-sorts raw edge features (edges_s[pos] = edges[e])
__global__ __launch_bounds__(256) void scatter_kernel(
    const int* __restrict__ send, const int* __restrict__ recv,
    const float* __restrict__ edges_raw, int* __restrict__ cursor,
    float* __restrict__ edges_s, int* __restrict__ sendp, int* __restrict__ recvp, int E) {
    int e = blockIdx.x * 256 + threadIdx.x;
    if (e >= E) return;
    int r = recv[e];
    int pos = atomicAdd(&cursor[r], 1);
    sendp[pos] = send[e]; recvp[pos] = r;
    edges_s[(size_t)pos * 3]     = edges_raw[(size_t)e * 3];
    edges_s[(size_t)pos * 3 + 1] = edges_raw[(size_t)e * 3 + 1];
    edges_s[(size_t)pos * 3 + 2] = edges_raw[(size_t)e * 3 + 2];
}
// after scatter: cursor[i] == end offset of node i's segment (CSR row end)

// ---------------- segment-sum (4x-wide): recvb[i] = sum of newe rows ----------------
// One wave per node: 4 row-groups x 16 col-chunks; bf16x8 per lane per row.
__global__ __launch_bounds__(256) void segsum_kernel(const bf16* __restrict__ newe,
                                                     const int* __restrict__ endoff,
                                                     bf16* __restrict__ recvb, int N) {
    int node = blockIdx.x * 4 + (threadIdx.x >> 6);
    if (node >= N) return;
    int lane = threadIdx.x & 63;
    int g = lane >> 4, cl = lane & 15;
    int start = (node == 0) ? 0 : endoff[node - 1];
    int end = endoff[node];
    float s[8] = {0, 0, 0, 0, 0, 0, 0, 0};
    for (int e = start + g; e < end; e += 4) {
        bf16x8 v = *(const bf16x8*)(newe + (size_t)e * 128 + cl * 8);
#pragma unroll
        for (int j = 0; j < 8; ++j) s[j] += (float)v[j];
    }
#pragma unroll
    for (int j = 0; j < 8; ++j) {
        s[j] += __shfl_xor(s[j], 16);
        s[j] += __shfl_xor(s[j], 32);
    }
    if (g == 0) {
        bf16x8 o;
#pragma unroll
        for (int j = 0; j < 8; ++j) o[j] = (bf16)s[j];
        *(bf16x8*)(recvb + (size_t)node * 128 + cl * 8) = o;
    }
}

// ---------------- edge megakernel (r10 exact): embed(recompute) [+LN] + step MLP ----------------
// STEP 0: new_e1 = MLP_s0(concat(eh0, nh_s, nh_r)+g)        ; newe <- new_e1
// STEP 1: eh1 = LN(eh0+newe1); new_e2 = MLP_s1(concat(...)) ; newe <- new_e2 (in-place)
template <int STEP>
__global__ __launch_bounds__(256, 5) void edge_kernel(
    const float* __restrict__ edges_s,
    const int* __restrict__ sendp, const int* __restrict__ recvp,
    const bf16* __restrict__ nh_b, bf16* __restrict__ newe,
    const bf16* __restrict__ We0, const float* __restrict__ be0,
    const bf16* __restrict__ We1, const float* __restrict__ be1,
    const float* __restrict__ ln_s, const float* __restrict__ ln_b,
    const bf16* __restrict__ Ws0, const float* __restrict__ bs0,
    const bf16* __restrict__ Ws1, const float* __restrict__ bs1,
    int E)
{
    __shared__ __align__(16) bf16 Hsep[4 * 16 * 136];
    const int tid = threadIdx.x, lane = tid & 63, w = tid >> 6;
    const int n16 = lane & 15, quad = lane >> 4;
    const int m0 = blockIdx.x * 64;
    int m = m0 + w * 16 + n16; if (m >= E) m = E - 1;
    const int sIdx = sendp[m], rIdx = recvp[m];

    bf16* Hw = &Hsep[w * 16 * 136];
    const f32x4 z = {0.0f, 0.0f, 0.0f, 0.0f};
    f32x4 acc[8];

    // ---- embed GEMM1 (K=32; quad0 carries the 3 raw feats, sorted order) ----
#pragma unroll
    for (int t = 0; t < 8; ++t) acc[t] = z;
    {
        bf16x8 a;
#pragma unroll
        for (int j = 0; j < 8; ++j) a[j] = (bf16)0.0f;
        if (quad == 0) {
            a[0] = (bf16)edges_s[(size_t)m * 3];
            a[1] = (bf16)edges_s[(size_t)m * 3 + 1];
            a[2] = (bf16)edges_s[(size_t)m * 3 + 2];
        }
        const bf16* bp = We0 + ((size_t)(quad * 128 + n16)) * 8;
#pragma unroll
        for (int t = 0; t < 8; ++t) {
            bf16x8 b = *(const bf16x8*)(bp + t * 128);
            acc[t] = __builtin_amdgcn_mfma_f32_16x16x32_bf16(a, b, acc[t], 0, 0, 0);
        }
    }
    // gelu + be0 -> Hw (A-layout)
#pragma unroll
    for (int t = 0; t < 8; ++t) {
        float bb = be0[t * 16 + n16];
#pragma unroll
        for (int r = 0; r < 4; ++r)
            Hw[(quad * 4 + r) * 136 + t * 16 + n16] = (bf16)gelu_t(acc[t][r] + bb);
    }
    // ---- embed GEMM2 (K=128) -> eh0 (C-layout) ----
#pragma unroll
    for (int t = 0; t < 8; ++t) acc[t] = z;
#pragma unroll
    for (int kc = 0; kc < 128; kc += 32) {
        bf16x8 a = *(const bf16x8*)&Hw[n16 * 136 + kc + quad * 8];
        const bf16* bp = We1 + ((size_t)(((kc >> 3) + quad) * 128 + n16)) * 8;
#pragma unroll
        for (int t = 0; t < 8; ++t) {
            bf16x8 b = *(const bf16x8*)(bp + t * 128);
            acc[t] = __builtin_amdgcn_mfma_f32_16x16x32_bf16(a, b, acc[t], 0, 0, 0);
        }
    }
    // eh0 -> Hw (A-layout, bf16)
#pragma unroll
    for (int t = 0; t < 8; ++t) {
        float bb = be1[t * 16 + n16];
#pragma unroll
        for (int r = 0; r < 4; ++r)
            Hw[(quad * 4 + r) * 136 + t * 16 + n16] = (bf16)(acc[t][r] + bb);
    }
    bf16x8 a1[4];
#pragma unroll
    for (int c = 0; c < 4; ++c)
        a1[c] = *(const bf16x8*)&Hw[n16 * 136 + c * 32 + quad * 8];

    if constexpr (STEP == 1) {
        // eh1 = LN(eh0 + newe1) on A-fragments; full row in lanes {n16,+16,+32,+48}
        float x[4][8];
        float sm = 0.0f, sq = 0.0f;
#pragma unroll
        for (int c = 0; c < 4; ++c) {
            bf16x8 ne = *(const bf16x8*)(newe + (size_t)m * 128 + c * 32 + quad * 8);
#pragma unroll
            for (int j = 0; j < 8; ++j) {
                float v = (float)a1[c][j] + (float)ne[j];
                x[c][j] = v; sm += v; sq += v * v;
            }
        }
        sm += __shfl_xor(sm, 16); sq += __shfl_xor(sq, 16);
        sm += __shfl_xor(sm, 32); sq += __shfl_xor(sq, 32);
        float mean = sm * (1.0f / 128.0f);
        float inv = rsqrtf(sq * (1.0f / 128.0f) - mean * mean + 1e-6f);
#pragma unroll
        for (int c = 0; c < 4; ++c)
#pragma unroll
            for (int j = 0; j < 8; ++j) {
                int col = c * 32 + quad * 8 + j;
                a1[c][j] = (bf16)((x[c][j] - mean) * inv * ln_s[col] + ln_b[col]);
            }
    }

    // ---- step GEMM1: K=384 = [eh | nh[send] | nh[recv]] ----
#pragma unroll
    for (int t = 0; t < 8; ++t) acc[t] = z;
#pragma unroll
    for (int c = 0; c < 12; ++c) {
        const int k0 = (c & 3) * 32 + quad * 8;
        bf16x8 af;
        if (c < 4)      af = a1[c];
        else if (c < 8) af = *(const bf16x8*)(nh_b + (size_t)sIdx * 128 + k0);
        else            af = *(const bf16x8*)(nh_b + (size_t)rIdx * 128 + k0);
        const bf16* bp = Ws0 + ((size_t)((c * 4 + quad) * 128 + n16)) * 8;
#pragma unroll
        for (int t = 0; t < 8; ++t) {
            bf16x8 b = *(const bf16x8*)(bp + t * 128);
            acc[t] = __builtin_amdgcn_mfma_f32_16x16x32_bf16(af, b, acc[t], 0, 0, 0);
        }
    }
    // gelu + bs0 -> Hw
#pragma unroll
    for (int t = 0; t < 8; ++t) {
        float bb = bs0[t * 16 + n16];
#pragma unroll
        for (int r = 0; r < 4; ++r)
            Hw[(quad * 4 + r) * 136 + t * 16 + n16] = (bf16)gelu_t(acc[t][r] + bb);
    }
    // ---- step GEMM2 (K=128) -> new_e ----
#pragma unroll
    for (int t = 0; t < 8; ++t) acc[t] = z;
#pragma unroll
    for (int kc = 0; kc < 128; kc += 32) {
        bf16x8 a = *(const bf16x8*)&Hw[n16 * 136 + kc + quad * 8];
        const bf16* bp = Ws1 + ((size_t)(((kc >> 3) + quad) * 128 + n16)) * 8;
#pragma unroll
        for (int t = 0; t < 8; ++t) {
            bf16x8 b = *(const bf16x8*)(bp + t * 128);
            acc[t] = __builtin_amdgcn_mfma_f32_16x16x32_bf16(a, b, acc[t], 0, 0, 0);
        }
    }
    // store new_e (guarded)
#pragma unroll
    for (int t = 0; t < 8; ++t) {
        float bb = bs1[t * 16 + n16];
#pragma unroll
        for (int r = 0; r < 4; ++r) {
            int row = m0 + w * 16 + quad * 4 + r;
            if (row < E)
                newe[(size_t)row * 128 + t * 16 + n16] = (bf16)(acc[t][r] + bb);
        }
    }
}

// ---------------- node kernels ----------------
// MODE 0: embed nodes  (K1=32, raw 7)  fp32 in  -> bf16 nh_b
// MODE 3: node update  (K1=256) bf16 nh_b + bf16 recvb -> bf16 nh_b in-place, skip+LN
// MODE 5: node update + FUSED decode: LN out -> Hw -> GEMM1(Wd0) -> gelu ->
//         [128,3] dot (dW1,db1) -> fp32 out[N,3]. No nh_b store.
template <int MODE, int K1, int RAWF>
__global__ __launch_bounds__(256, 4) void mlp2_kernel(
    const void* __restrict__ Araw0v, const bf16* __restrict__ Araw1b,
    const bf16* __restrict__ W0p, const float* __restrict__ b0,
    const bf16* __restrict__ W1p, const float* __restrict__ b1,
    const float* __restrict__ ln_s, const float* __restrict__ ln_b,
    const bf16* __restrict__ Wd0, const float* __restrict__ db0,
    const float* __restrict__ dW1, const float* __restrict__ db1,
    void* out0v, int Mtotal)
{
    __shared__ __align__(16) bf16 Hsep[4 * 16 * 136];

    const int tid = threadIdx.x, lane = tid & 63, w = tid >> 6;
    const int n16 = lane & 15, quad = lane >> 4;
    const int m0 = blockIdx.x * 64;

    const float* Araw0f = (const float*)Araw0v;
    const bf16*  Araw0b = (const bf16*)Araw0v;
    float* out0f = (float*)out0v;
    bf16*  out0b = (bf16*)out0v;

    int m = m0 + w * 16 + n16;
    if (m >= Mtotal) m = Mtotal - 1;

    const f32x4 z = {0.0f, 0.0f, 0.0f, 0.0f};
    f32x4 acc[8];
#pragma unroll
    for (int t = 0; t < 8; ++t) acc[t] = z;

    // ---- GEMM1 ----
#pragma unroll
    for (int c = 0; c < K1 / 32; ++c) {
        const int k0 = c * 32 + quad * 8;
        bf16x8 a;
        if constexpr (MODE == 3 || MODE == 5) {
            if (c < 4) a = *(const bf16x8*)(Araw0b + (size_t)m * 128 + k0);
            else       a = *(const bf16x8*)(Araw1b + (size_t)m * 128 + (k0 - 128));
        } else {  // MODE 0: RAWF raw features (<8), only quad 0 nonzero
#pragma unroll
            for (int j = 0; j < 8; ++j) a[j] = (bf16)0.0f;
            if (quad == 0) {
#pragma unroll
                for (int j = 0; j < RAWF; ++j)
                    a[j] = (bf16)Araw0f[(size_t)m * RAWF + j];
            }
        }
        const bf16* bp = W0p + ((size_t)((c * 4 + quad) * 128 + n16)) * 8;
#pragma unroll
        for (int t = 0; t < 8; ++t) {
            bf16x8 b = *(const bf16x8*)(bp + t * 128);
            acc[t] = __builtin_amdgcn_mfma_f32_16x16x32_bf16(a, b, acc[t], 0, 0, 0);
        }
    }

    float b0v[8];
#pragma unroll
    for (int t = 0; t < 8; ++t) b0v[t] = b0[t * 16 + n16];

    // hidden -> A-layout via wave-private LDS slab
    bf16* Hw = &Hsep[w * 16 * 136];
#pragma unroll
    for (int t = 0; t < 8; ++t)
#pragma unroll
        for (int r = 0; r < 4; ++r)
            Hw[(quad * 4 + r) * 136 + t * 16 + n16] = (bf16)gelu_t(acc[t][r] + b0v[t]);

    // ---- GEMM2 (K=128) ----
#pragma unroll
    for (int t = 0; t < 8; ++t) acc[t] = z;
#pragma unroll
    for (int kc = 0; kc < 128; kc += 32) {
        bf16x8 a = *(const bf16x8*)&Hw[n16 * 136 + kc + quad * 8];
        const bf16* bp = W1p + ((size_t)(((kc >> 3) + quad) * 128 + n16)) * 8;
#pragma unroll
        for (int t = 0; t < 8; ++t) {
            bf16x8 b = *(const bf16x8*)(bp + t * 128);
            acc[t] = __builtin_amdgcn_mfma_f32_16x16x32_bf16(a, b, acc[t], 0, 0, 0);
        }
    }

    if constexpr (MODE == 0) {  // embed nodes: plain bf16 store
#pragma unroll
        for (int t = 0; t < 8; ++t) {
            float b1v = b1[t * 16 + n16];
#pragma unroll
            for (int r = 0; r < 4; ++r) {
                int row = m0 + w * 16 + quad * 4 + r;
                if (row < Mtotal)
                    out0b[(size_t)row * 128 + t * 16 + n16] = (bf16)(acc[t][r] + b1v);
            }
        }
        return;
    }

    // ---- MODE 3/5 epilogue: skip + LayerNorm ----
    float b1v[8], scl[8], bia[8];
#pragma unroll
    for (int t = 0; t < 8; ++t) {
        int col = t * 16 + n16;
        b1v[t] = b1[col]; scl[t] = ln_s[col]; bia[t] = ln_b[col];
    }
    int rowg[4];
#pragma unroll
    for (int r = 0; r < 4; ++r) rowg[r] = m0 + w * 16 + quad * 4 + r;
    float x[8][4];
    float sm[4] = {0, 0, 0, 0}, sq[4] = {0, 0, 0, 0};
#pragma unroll
    for (int t = 0; t < 8; ++t) {
        int col = t * 16 + n16;
#pragma unroll
        for (int r = 0; r < 4; ++r) {
            bool ok = rowg[r] < Mtotal;
            float v = acc[t][r] + b1v[t];
            float old = ok ? (float)Araw0b[(size_t)rowg[r] * 128 + col] : 0.0f;
            float xx = old + v;
            x[t][r] = xx; sm[r] += xx; sq[r] += xx * xx;
        }
    }
#pragma unroll
    for (int mm = 1; mm < 16; mm <<= 1)
#pragma unroll
        for (int r = 0; r < 4; ++r) {
            sm[r] += __shfl_xor(sm[r], mm);
            sq[r] += __shfl_xor(sq[r], mm);
        }
    float mean[4], inv[4];
#pragma unroll
    for (int r = 0; r < 4; ++r) {
        mean[r] = sm[r] * (1.0f / 128.0f);
        float var = sq[r] * (1.0f / 128.0f) - mean[r] * mean[r];
        inv[r] = rsqrtf(var + 1e-6f);
    }

    if constexpr (MODE == 3) {
#pragma unroll
        for (int t = 0; t < 8; ++t)
#pragma unroll
            for (int r = 0; r < 4; ++r)
                if (rowg[r] < Mtotal)
                    out0b[(size_t)rowg[r] * 128 + t * 16 + n16] =
                        (bf16)((x[t][r] - mean[r]) * inv[r] * scl[t] + bia[t]);
        return;
    }

    // ---- MODE 5: fused decode. LN out -> Hw (A-layout), GEMM1(Wd0), dot dW1 ----
#pragma unroll
    for (int t = 0; t < 8; ++t)
#pragma unroll
        for (int r = 0; r < 4; ++r)
            Hw[(quad * 4 + r) * 136 + t * 16 + n16] =
                (bf16)((x[t][r] - mean[r]) * inv[r] * scl[t] + bia[t]);

#pragma unroll
    for (int t = 0; t < 8; ++t) acc[t] = z;
#pragma unroll
    for (int kc = 0; kc < 128; kc += 32) {
        bf16x8 a = *(const bf16x8*)&Hw[n16 * 136 + kc + quad * 8];
        const bf16* bp = Wd0 + ((size_t)(((kc >> 3) + quad) * 128 + n16)) * 8;
#pragma unroll
        for (int t = 0; t < 8; ++t) {
            bf16x8 b = *(const bf16x8*)(bp + t * 128);
            acc[t] = __builtin_amdgcn_mfma_f32_16x16x32_bf16(a, b, acc[t], 0, 0, 0);
        }
    }
    {
        float p[4][3];
#pragma unroll
        for (int r = 0; r < 4; ++r) { p[r][0] = 0; p[r][1] = 0; p[r][2] = 0; }
#pragma unroll
        for (int t = 0; t < 8; ++t) {
            int col = t * 16 + n16;
            float bb = db0[col];
            float w0 = dW1[col * 3 + 0], w1 = dW1[col * 3 + 1], w2 = dW1[col * 3 + 2];
#pragma unroll
            for (int r = 0; r < 4; ++r) {
                float h = gelu_t(acc[t][r] + bb);
                p[r][0] += h * w0; p[r][1] += h * w1; p[r][2] += h * w2;
            }
        }
#pragma unroll
        for (int mm = 1; mm < 16; mm <<= 1)
#pragma unroll
            for (int r = 0; r < 4; ++r) {
                p[r][0] += __shfl_xor(p[r][0], mm);
                p[r][1] += __shfl_xor(p[r][1], mm);
                p[r][2] += __shfl_xor(p[r][2], mm);
            }
        if (n16 < 3) {
            float bb = db1[n16];
#pragma unroll
            for (int r = 0; r < 4; ++r)
                if (rowg[r] < Mtotal)
                    out0f[(size_t)rowg[r] * 3 + n16] = p[r][n16] + bb;
        }
    }
}

extern "C" void kernel_launch(void* const* d_in, const int* in_sizes, int n_in,
                              void* d_out, int out_size, void* d_ws, size_t ws_size,
                              hipStream_t stream) {
    const float* nodes   = (const float*)d_in[0];
    const float* edges   = (const float*)d_in[1];
    const float* glob    = (const float*)d_in[2];
    const int*   senders = (const int*)d_in[3];
    const int*   recvrs  = (const int*)d_in[4];
    const float* ne_W0 = (const float*)d_in[5],  *ne_b0 = (const float*)d_in[6];
    const float* ne_W1 = (const float*)d_in[7],  *ne_b1 = (const float*)d_in[8];
    const float* ee_W0 = (const float*)d_in[9],  *ee_b0 = (const float*)d_in[10];
    const float* ee_W1 = (const float*)d_in[11], *ee_b1 = (const float*)d_in[12];
    const float* eu_W0 = (const float*)d_in[13], *eu_b0 = (const float*)d_in[14];
    const float* eu_W1 = (const float*)d_in[15], *eu_b1 = (const float*)d_in[16];
    const float* nu_W0 = (const float*)d_in[17], *nu_b0 = (const float*)d_in[18];
    const float* nu_W1 = (const float*)d_in[19], *nu_b1 = (const float*)d_in[20];
    const float* ln_s  = (const float*)d_in[21], *ln_b  = (const float*)d_in[22];
    const float* dc_W0 = (const float*)d_in[23], *dc_b0 = (const float*)d_in[24];
    const float* dc_W1 = (const float*)d_in[25], *dc_b1 = (const float*)d_in[26];

    const int N = 50000, E = 500000;

    const int KD[13] = {32, 128, 32, 128, 384, 384, 128, 128, 256, 256, 128, 128, 128};
    const int KC[13] = {7, 128, 3, 128, 384, 384, 128, 128, 256, 256, 128, 128, 128};
    int pre[14]; pre[0] = 0;
    for (int i = 0; i < 13; ++i) pre[i + 1] = pre[i] + KD[i] * 128;
    const int totalPack = pre[13];

    char* ws = (char*)d_ws;
    size_t off = 0;
    auto alloc = [&](size_t bytes) -> char* {
        char* p = ws + off;
        off = (off + bytes + 255) & ~(size_t)255;
        return p;
    };
    bf16*  Wp      = (bf16*)alloc((size_t)totalPack * 2);
    float* b0e_eu  = (float*)alloc(2 * 128 * 4);
    float* b0e_nu  = (float*)alloc(2 * 128 * 4);
    bf16*  nh_b    = (bf16*)alloc((size_t)N * 128 * 2);      // 12.8 MB
    bf16*  recvb   = (bf16*)alloc((size_t)N * 128 * 2);      // 12.8 MB
    bf16*  newe    = (bf16*)alloc((size_t)E * 128 * 2);      // 128 MB
    int*   deg     = (int*)alloc((size_t)N * 4);
    int*   cursor  = (int*)alloc((size_t)N * 4);
    int*   bsum    = (int*)alloc(256 * 4);
    float* edges_s = (float*)alloc((size_t)E * 3 * 4);       // 6 MB sorted raw feats
    int*   sendp   = (int*)alloc((size_t)E * 4);
    int*   recvp   = (int*)alloc((size_t)E * 4);
    // total ~164 MB (proven-good envelope)

    if (off > ws_size) return;  // clean diagnostic instead of OOB fault

    PackArgs pa;
    const float* srcs[13] = {
        ne_W0, ne_W1, ee_W0, ee_W1,
        eu_W0, eu_W0 + (size_t)386 * 128,
        eu_W1, eu_W1 + (size_t)128 * 128,
        nu_W0, nu_W0 + (size_t)258 * 128,
        nu_W1, nu_W1 + (size_t)128 * 128,
        dc_W0};
    for (int i = 0; i < 13; ++i) { pa.d[i].src = srcs[i]; pa.d[i].Kcopy = KC[i]; pa.d[i].dstOff = pre[i]; }

    pack_all_kernel<<<(totalPack + 255) / 256, 256, 0, stream>>>(pa, Wp, totalPack);
    fold_bias_kernel<<<1, 128, 0, stream>>>(glob, eu_W0, eu_b0, nu_W0, nu_b0, b0e_eu, b0e_nu);

    // ---- receiver counting-sort ----
    const int gEdge = (E + 255) / 256;
    const int nb = (N + 255) / 256;
    zero_kernel<<<(N / 4 + 255) / 256, 256, 0, stream>>>((float4*)deg, N / 4);
    hist_kernel<<<gEdge, 256, 0, stream>>>(recvrs, deg, E);
    scan_part_kernel<<<nb, 256, 0, stream>>>(deg, cursor, bsum, N);
    scan_top_kernel<<<1, 256, 0, stream>>>(bsum, nb);
    scan_add_kernel<<<nb, 256, 0, stream>>>(cursor, bsum, N);
    scatter_kernel<<<gEdge, 256, 0, stream>>>(senders, recvrs, edges, cursor,
                                              edges_s, sendp, recvp, E);
    // cursor now holds CSR end-offsets

    const int gN = (N + 63) / 64, gE = (E + 63) / 64;
    mlp2_kernel<0, 32, 7><<<gN, 256, 0, stream>>>(
        nodes, nullptr, Wp + pre[0], ne_b0, Wp + pre[1], ne_b1,
        nullptr, nullptr, nullptr, nullptr, nullptr, nullptr, nh_b, N);

    for (int s = 0; s < 2; ++s) {
        if (s == 0)
            edge_kernel<0><<<gE, 256, 0, stream>>>(
                edges_s, sendp, recvp, nh_b, newe,
                Wp + pre[2], ee_b0, Wp + pre[3], ee_b1, ln_s, ln_b,
                Wp + pre[4], b0e_eu, Wp + pre[6], eu_b1, E);
        else
            edge_kernel<1><<<gE, 256, 0, stream>>>(
                edges_s, sendp, recvp, nh_b, newe,
                Wp + pre[2], ee_b0, Wp + pre[3], ee_b1, ln_s, ln_b,
                Wp + pre[5], b0e_eu + 128, Wp + pre[7], eu_b1 + 128, E);
        segsum_kernel<<<(N + 3) / 4, 256, 0, stream>>>(newe, cursor, recvb, N);
        if (s == 0)
            mlp2_kernel<3, 256, 0><<<gN, 256, 0, stream>>>(
                nh_b, recvb, Wp + pre[8], b0e_nu,
                Wp + pre[10], nu_b1, ln_s, ln_b,
                nullptr, nullptr, nullptr, nullptr, nh_b, N);
        else
            mlp2_kernel<5, 256, 0><<<gN, 256, 0, stream>>>(
                nh_b, recvb, Wp + pre[9], b0e_nu + 128,
                Wp + pre[11], nu_b1 + 128, ln_s, ln_b,
                Wp + pre[12], dc_b0, dc_W1, dc_b1, d_out, N);
    }
}